// Round 13
// baseline (310.128 us; speedup 1.0000x reference)
//
#include <hip/hip_runtime.h>
#include <math.h>

#define H 64
#define NXCD 8
#define CH 2048
#define CAP 8192

typedef __attribute__((ext_vector_type(8))) short short8;
typedef __attribute__((ext_vector_type(4))) float f32x4;

__device__ inline ushort f2bf(float f) {
    union { float f; unsigned u; } v;
    v.f = f;
    unsigned r = v.u + 0x7FFFu + ((v.u >> 16) & 1u);
    return (ushort)(r >> 16);
}

// ---------- Pass 1: histogram of destinations (int4-vectorized reads) ----------
__global__ void k_hist(const int* __restrict__ dst, unsigned* __restrict__ cnt, int E) {
    int i = blockIdx.x * blockDim.x + threadIdx.x;
    int st = gridDim.x * blockDim.x;
    int E4 = E >> 2;
    const int4* d4 = (const int4*)dst;
    for (int k = i; k < E4; k += st) {
        int4 v = d4[k];
        atomicAdd(&cnt[v.x], 1u);
        atomicAdd(&cnt[v.y], 1u);
        atomicAdd(&cnt[v.z], 1u);
        atomicAdd(&cnt[v.w], 1u);
    }
    for (int k = (E4 << 2) + i; k < E; k += st) atomicAdd(&cnt[dst[k]], 1u);
}

// ---------- Hierarchical exclusive scan ----------
__global__ __launch_bounds__(1024) void k_scanA(const unsigned* __restrict__ cnt,
                                                unsigned* __restrict__ base,
                                                unsigned* __restrict__ bsum, int N) {
    __shared__ unsigned wsum[16];
    int i = blockIdx.x * 1024 + threadIdx.x;
    unsigned v = (i < N) ? cnt[i] : 0u;
    int lane = threadIdx.x & 63, w = threadIdx.x >> 6;
    unsigned x = v;
#pragma unroll
    for (int off = 1; off < 64; off <<= 1) {
        unsigned y = __shfl_up(x, off, 64);
        if (lane >= off) x += y;
    }
    if (lane == 63) wsum[w] = x;
    __syncthreads();
    if (threadIdx.x < 16) {
        unsigned s = wsum[threadIdx.x];
#pragma unroll
        for (int off = 1; off < 16; off <<= 1) {
            unsigned y = __shfl_up(s, off, 16);
            if ((threadIdx.x & 15) >= off) s += y;
        }
        wsum[threadIdx.x] = s;
    }
    __syncthreads();
    unsigned wbase = (w > 0) ? wsum[w - 1] : 0u;
    if (i < N) base[i] = wbase + x - v;
    if (threadIdx.x == 1023) bsum[blockIdx.x] = wsum[15];
}

__global__ __launch_bounds__(1024) void k_scanB(const unsigned* __restrict__ bsum,
                                                unsigned* __restrict__ boff, int nb) {
    __shared__ unsigned wsum[16];
    int i = threadIdx.x;
    unsigned v = (i < nb) ? bsum[i] : 0u;
    int lane = i & 63, w = i >> 6;
    unsigned x = v;
#pragma unroll
    for (int off = 1; off < 64; off <<= 1) {
        unsigned y = __shfl_up(x, off, 64);
        if (lane >= off) x += y;
    }
    if (lane == 63) wsum[w] = x;
    __syncthreads();
    if (i < 16) {
        unsigned s = wsum[i];
#pragma unroll
        for (int off = 1; off < 16; off <<= 1) {
            unsigned y = __shfl_up(s, off, 16);
            if ((i & 15) >= off) s += y;
        }
        wsum[i] = s;
    }
    __syncthreads();
    unsigned wbase = (w > 0) ? wsum[w - 1] : 0u;
    if (i < nb) boff[i] = wbase + x - v;
}

__global__ void k_scanC(unsigned* __restrict__ base, unsigned* __restrict__ cursor,
                        const unsigned* __restrict__ boff, int N, int E) {
    int i = blockIdx.x * blockDim.x + threadIdx.x;
    int st = gridDim.x * blockDim.x;
    for (; i < N; i += st) {
        unsigned b = base[i] + boff[i >> 10];
        base[i] = b;
        cursor[i] = b;
    }
    if (blockIdx.x == 0 && threadIdx.x == 0) base[N] = (unsigned)E;
}

// ---------- bstart/bcur init: bmeta[0..8]=bstart, bmeta[16..23]=bcur ----------
__global__ void k_binit(const unsigned* __restrict__ base, unsigned* __restrict__ bmeta,
                        int N, int partsize) {
    int p = threadIdx.x;
    if (p <= NXCD) {
        int lo = p * partsize;
        if (lo > N) lo = N;
        unsigned b = base[lo];
        bmeta[p] = b;
        if (p < NXCD) bmeta[16 + p] = b;
    }
}

// ---------- Pass 2a: coarse bin by dst-part (verified R12) ----------
__global__ __launch_bounds__(256) void k_bin(const int* __restrict__ dst,
                                             const int* __restrict__ src,
                                             const float* __restrict__ t,
                                             unsigned* __restrict__ bcur,
                                             int2* __restrict__ pay2,
                                             int* __restrict__ dbin,
                                             int E, int partsize) {
    __shared__ unsigned lcnt[NXCD];
    __shared__ unsigned lofs[NXCD];
    int e0 = blockIdx.x * CH;
    int e1 = min(e0 + CH, E);
    if (threadIdx.x < NXCD) lcnt[threadIdx.x] = 0;
    __syncthreads();
    for (int i = e0 + threadIdx.x; i < e1; i += 256) {
        int d = dst[i];
        int p = 0;
#pragma unroll
        for (int k = 1; k < NXCD; ++k) p += (d >= k * partsize);
        atomicAdd(&lcnt[p], 1u);
    }
    __syncthreads();
    if (threadIdx.x < NXCD)
        lofs[threadIdx.x] = atomicAdd(&bcur[threadIdx.x], lcnt[threadIdx.x]);
    __syncthreads();
    const float inv = 1.0f / (0.5f + 1e-8f);
    for (int i = e0 + threadIdx.x; i < e1; i += 256) {
        int d = dst[i];
        int p = 0;
#pragma unroll
        for (int k = 1; k < NXCD; ++k) p += (d >= k * partsize);
        unsigned u = atomicAdd(&lofs[p], 1u);
        dbin[u] = d;
        pay2[u] = make_int2(src[i], __float_as_int(__expf(t[i] * inv)));
    }
}

// ---------- Pass 2b: LDS-staged fine scatter. Sequential global writes only ----------
// Block (p, sub) owns dst range [d0,d1). It streams part p's bin, scatters matches
// into LDS via LDS-only cursors (position relative to base[d0]), then writes the
// assembled slab to payload[base[d0]..base[d1]) fully coalesced.
__global__ __launch_bounds__(256) void k_fine_lds(const unsigned* __restrict__ base,
                                                  const unsigned* __restrict__ bmeta,
                                                  const int* __restrict__ dbin,
                                                  const int2* __restrict__ pay2,
                                                  int2* __restrict__ payload,
                                                  int N, int partsize, int nsub) {
    int p = blockIdx.x & (NXCD - 1);
    int sub = blockIdx.x >> 3;
    int plo = p * partsize;
    int phi = min(plo + partsize, N);
    int subsz = (partsize + nsub - 1) / nsub;
    int d0 = plo + sub * subsz;
    if (d0 >= phi) return;  // uniform across block
    int d1 = min(d0 + subsz, phi);
    int nd = d1 - d0;

    __shared__ int2 sPay[CAP];
    __shared__ unsigned lrel[512];  // base[d0+i] - base[d0]
    __shared__ unsigned lcur[512];

    unsigned g0 = base[d0];
    unsigned g1 = base[d1];
    int cnt = (int)(g1 - g0);
    for (int i = threadIdx.x; i < nd; i += 256) {
        lrel[i] = base[d0 + i] - g0;
        lcur[i] = 0;
    }
    __syncthreads();

    int b0 = (int)bmeta[p], b1 = (int)bmeta[p + 1];
    for (int i = b0 + threadIdx.x; i < b1; i += 256) {
        int d = dbin[i];
        if (d >= d0 && d < d1) {
            unsigned lpos = lrel[d - d0] + atomicAdd(&lcur[d - d0], 1u);
            int2 v = pay2[i];
            if (lpos < CAP) sPay[lpos] = v;
            else payload[g0 + lpos] = v;  // spill (correctness only; ~never taken)
        }
    }
    __syncthreads();
    int wn = min(cnt, CAP);
    for (int j = threadIdx.x; j < wn; j += 256) payload[g0 + j] = sPay[j];
}

// ---------- Fallback permutes (R10-proven) ----------
__global__ void k_permute_part(const int* __restrict__ dst, const int* __restrict__ src,
                               const float* __restrict__ t, unsigned* __restrict__ cursor,
                               int2* __restrict__ payload, int E, int N) {
    const float inv = 1.0f / (0.5f + 1e-8f);
    int part = blockIdx.x & (NXCD - 1);
    int nslice = gridDim.x >> 3;
    int sblk = blockIdx.x >> 3;
    int lo = (int)((long long)part * N / NXCD);
    int hi = (int)((long long)(part + 1) * N / NXCD);
    int e0 = (int)((long long)sblk * E / nslice);
    int e1 = (int)((long long)(sblk + 1) * E / nslice);
    for (int i = e0 + threadIdx.x; i < e1; i += blockDim.x) {
        int d = dst[i];
        if (d >= lo && d < hi) {
            unsigned pos = atomicAdd(&cursor[d], 1u);
            float e = __expf(t[i] * inv);
            payload[pos] = make_int2(src[i], __float_as_int(e));
        }
    }
}

__global__ void k_permute_pack(const int* __restrict__ dst, const int* __restrict__ src,
                               const float* __restrict__ t, unsigned* __restrict__ cursor,
                               int2* __restrict__ payload, int E) {
    const float inv = 1.0f / (0.5f + 1e-8f);
    int i = blockIdx.x * blockDim.x + threadIdx.x;
    int st = gridDim.x * blockDim.x;
    for (; i < E; i += st) {
        unsigned pos = atomicAdd(&cursor[dst[i]], 1u);
        float e = __expf(t[i] * inv);
        payload[pos] = make_int2(src[i], __float_as_int(e));
    }
}

// ---------- Pre-transform: y(bf16) = x @ W^T via MFMA 16x16x32 bf16 (verified R8) ----------
__global__ __launch_bounds__(256) void k_xform_mfma(const float* __restrict__ x,
                                                    const float* __restrict__ W,
                                                    ushort* __restrict__ y, int M) {
    int wid = (blockIdx.x * blockDim.x + threadIdx.x) >> 6;
    int lane = threadIdx.x & 63;
    int n0 = wid * 16;
    if (n0 >= M) return;
    int r = lane & 15, g = lane >> 4;

    short8 bfrag[4][2];
#pragma unroll
    for (int ct = 0; ct < 4; ++ct) {
#pragma unroll
        for (int kh = 0; kh < 2; ++kh) {
            const float* wp = &W[(size_t)(ct * 16 + r) * 64 + kh * 32 + g * 8];
            float4 w0 = *(const float4*)wp;
            float4 w1 = *(const float4*)(wp + 4);
            short8 bf;
            bf[0] = (short)f2bf(w0.x); bf[1] = (short)f2bf(w0.y);
            bf[2] = (short)f2bf(w0.z); bf[3] = (short)f2bf(w0.w);
            bf[4] = (short)f2bf(w1.x); bf[5] = (short)f2bf(w1.y);
            bf[6] = (short)f2bf(w1.z); bf[7] = (short)f2bf(w1.w);
            bfrag[ct][kh] = bf;
        }
    }
    int xr = n0 + r;
    if (xr >= M) xr = M - 1;
    const float* xp = &x[(size_t)xr * 64 + g * 8];
    short8 afrag[2];
#pragma unroll
    for (int kh = 0; kh < 2; ++kh) {
        float4 a0 = *(const float4*)(xp + kh * 32);
        float4 a1 = *(const float4*)(xp + kh * 32 + 4);
        short8 af;
        af[0] = (short)f2bf(a0.x); af[1] = (short)f2bf(a0.y);
        af[2] = (short)f2bf(a0.z); af[3] = (short)f2bf(a0.w);
        af[4] = (short)f2bf(a1.x); af[5] = (short)f2bf(a1.y);
        af[6] = (short)f2bf(a1.z); af[7] = (short)f2bf(a1.w);
        afrag[kh] = af;
    }
#pragma unroll
    for (int ct = 0; ct < 4; ++ct) {
        f32x4 acc = {0.f, 0.f, 0.f, 0.f};
        acc = __builtin_amdgcn_mfma_f32_16x16x32_bf16(afrag[0], bfrag[ct][0], acc, 0, 0, 0);
        acc = __builtin_amdgcn_mfma_f32_16x16x32_bf16(afrag[1], bfrag[ct][1], acc, 0, 0, 0);
#pragma unroll
        for (int q = 0; q < 4; ++q) {
            int row = n0 + g * 4 + q;
            if (row < M) y[(size_t)row * 64 + ct * 16 + r] = f2bf(acc[q]);
        }
    }
}

// ---------- Pass 3: weighted gather, 4 dests/wave, 16 lanes/dest (verified R10) ----------
__global__ __launch_bounds__(256) void k_gather4(const unsigned* __restrict__ base,
                                                 const long long* __restrict__ payload,
                                                 const uint2* __restrict__ y2,
                                                 float* __restrict__ out, int N) {
    int tid = blockIdx.x * blockDim.x + threadIdx.x;
    int lane = threadIdx.x & 63;
    int g = lane >> 4, f = lane & 15;
    int d = (tid >> 6) * 4 + g;
    if (d >= N) return;
    unsigned r0 = base[d], r1 = base[d + 1];
    int deg = (int)(r1 - r0);
    float acc0 = 0.f, acc1 = 0.f, acc2 = 0.f, acc3 = 0.f, ssum = 0.f;
    for (int it = 0; it < deg; it += 4) {
        float e[4];
        int s[4];
#pragma unroll
        for (int k2 = 0; k2 < 4; ++k2) {
            // memory-safe overread: payload region is followed by the y region in ws
            long long pl = __builtin_nontemporal_load(&payload[r0 + it + k2]);
            bool ok = (it + k2) < deg;
            e[k2] = ok ? __int_as_float((int)(pl >> 32)) : 0.f;
            s[k2] = ok ? (int)(pl & 0xFFFFFFFFll) : 0;
            ssum += e[k2];
        }
        uint2 v[4];
#pragma unroll
        for (int k2 = 0; k2 < 4; ++k2) v[k2] = y2[(size_t)s[k2] * 16 + f];
#pragma unroll
        for (int k2 = 0; k2 < 4; ++k2) {
            float x0 = __uint_as_float(v[k2].x << 16);
            float x1 = __uint_as_float(v[k2].x & 0xFFFF0000u);
            float x2 = __uint_as_float(v[k2].y << 16);
            float x3 = __uint_as_float(v[k2].y & 0xFFFF0000u);
            acc0 = fmaf(e[k2], x0, acc0);
            acc1 = fmaf(e[k2], x1, acc1);
            acc2 = fmaf(e[k2], x2, acc2);
            acc3 = fmaf(e[k2], x3, acc3);
        }
    }
    float rs = 1.0f / (ssum + 1e-16f);
    f32x4 o = {acc0 * rs, acc1 * rs, acc2 * rs, acc3 * rs};
    __builtin_nontemporal_store(o, (f32x4*)&out[(size_t)d * H + f * 4]);
}

// ---------- Fallback gather (verified R3/R5) ----------
__global__ __launch_bounds__(256) void k_gather_fb(const unsigned* __restrict__ base,
                                                   const int2* __restrict__ payload,
                                                   const float* __restrict__ x_src,
                                                   const float* __restrict__ W,
                                                   float* __restrict__ out, int N) {
    __shared__ float wt[H * H];
    for (int idx = threadIdx.x; idx < H * H; idx += blockDim.x) {
        int j = idx >> 6, k = idx & 63;
        wt[k * H + j] = W[idx];
    }
    __syncthreads();
    int lane = threadIdx.x & 63;
    int wid = (blockIdx.x * blockDim.x + threadIdx.x) >> 6;
    int nw = (gridDim.x * blockDim.x) >> 6;
    for (int d = wid; d < N; d += nw) {
        unsigned r0 = base[d], r1 = base[d + 1];
        int deg = (int)(r1 - r0);
        float acc = 0.0f, ssum = 0.0f;
        for (int c = 0; c < deg; c += 64) {
            int j = c + lane;
            int cd = min(64, deg - c);
            float e = 0.0f;
            int sidx = 0;
            if (j < deg) {
                int2 p = payload[r0 + j];
                sidx = p.x;
                e = __int_as_float(p.y);
            }
            float cs = e;
#pragma unroll
            for (int off = 32; off >= 1; off >>= 1) cs += __shfl_xor(cs, off, 64);
            ssum += cs;
            for (int q = 0; q < cd; q += 8) {
                float a[8];
                int sv[8];
                float v[8];
#pragma unroll
                for (int u = 0; u < 8; ++u) {
                    a[u] = __shfl(e, q + u, 64);
                    sv[u] = __shfl(sidx, q + u, 64);
                }
#pragma unroll
                for (int u = 0; u < 8; ++u) v[u] = x_src[(size_t)sv[u] * H + lane];
#pragma unroll
                for (int u = 0; u < 8; ++u) acc = fmaf(a[u], v[u], acc);
            }
        }
        acc *= 1.0f / (ssum + 1e-16f);
        float o = 0.0f;
#pragma unroll
        for (int k = 0; k < H; ++k) o = fmaf(__shfl(acc, k, 64), wt[k * H + lane], o);
        out[(size_t)d * H + lane] = o;
    }
}

extern "C" void kernel_launch(void* const* d_in, const int* in_sizes, int n_in,
                              void* d_out, int out_size, void* d_ws, size_t ws_size,
                              hipStream_t stream) {
    const float* x_src = (const float*)d_in[0];
    const float* W = (const float*)d_in[2];
    const int* edge_index = (const int*)d_in[3];
    const float* t = (const float*)d_in[4];

    int E = in_sizes[4];
    int N = in_sizes[1] / H;  // N_DST
    int M = in_sizes[0] / H;  // N_SRC
    const int* src = edge_index;
    const int* dst = edge_index + E;

    // ws layout: base[N+1] | cursor[N] | bsum[1024] | boff[1024] | bmeta[32]
    //            | payload int2[E] | y bf16[M*H] | pay2 int2[E] | dbin int[E]
    unsigned* base = (unsigned*)d_ws;
    unsigned* cursor = base + (size_t)N + 1;
    unsigned* bsum = cursor + N;
    unsigned* boff = bsum + 1024;
    unsigned* bmeta = boff + 1024;
    size_t pay_off = (((size_t)(2 * N + 2081)) * 4 + 7) & ~(size_t)7;
    int2* payload = (int2*)((char*)d_ws + pay_off);
    size_t y_off = (pay_off + (size_t)E * 8 + 15) & ~(size_t)15;
    ushort* y = (ushort*)((char*)d_ws + y_off);
    size_t p2_off = (y_off + (size_t)M * H * 2 + 7) & ~(size_t)7;
    int2* pay2 = (int2*)((char*)d_ws + p2_off);
    int* dbin = (int*)((char*)d_ws + p2_off + (size_t)E * 8);
    size_t end_off = p2_off + (size_t)E * 12;

    bool have_payload = (ws_size >= pay_off + (size_t)E * 8 + 32);
    bool have_y = (ws_size >= y_off + (size_t)M * H * 2);
    bool have_bin = (ws_size >= end_off);

    int nb = (N + 1023) / 1024;
    int partsize = (N + NXCD - 1) / NXCD;
    int nsub = (partsize + 383) / 384;  // dst sub-range <= 384 <= 512 (LDS arrays)
    if (nsub < 1) nsub = 1;

    hipMemsetAsync(cursor, 0, (size_t)N * sizeof(unsigned), stream);

    int blocks_e = (E + 255) / 256;
    if (blocks_e > 2048) blocks_e = 2048;

    k_hist<<<1024, 256, 0, stream>>>(dst, cursor, E);
    k_scanA<<<nb, 1024, 0, stream>>>(cursor, base, bsum, N);
    k_scanB<<<1, 1024, 0, stream>>>(bsum, boff, nb);
    k_scanC<<<512, 256, 0, stream>>>(base, cursor, boff, N, E);

    if (have_y && have_bin) {
        int xblocks = ((M + 15) / 16 * 64 + 255) / 256;
        k_xform_mfma<<<xblocks, 256, 0, stream>>>(x_src, W, y, M);
        k_binit<<<1, 16, 0, stream>>>(base, bmeta, N, partsize);
        int nbin = (E + CH - 1) / CH;
        k_bin<<<nbin, 256, 0, stream>>>(dst, src, t, bmeta + 16, pay2, dbin, E, partsize);
        k_fine_lds<<<NXCD * nsub, 256, 0, stream>>>(base, bmeta, dbin, pay2, payload,
                                                    N, partsize, nsub);
        int gblocks = (N + 15) / 16;
        k_gather4<<<gblocks, 256, 0, stream>>>(base, (const long long*)payload,
                                               (const uint2*)y, (float*)d_out, N);
    } else if (have_y) {
        int xblocks = ((M + 15) / 16 * 64 + 255) / 256;
        k_xform_mfma<<<xblocks, 256, 0, stream>>>(x_src, W, y, M);
        k_permute_part<<<2048, 256, 0, stream>>>(dst, src, t, cursor, payload, E, N);
        int gblocks = (N + 15) / 16;
        k_gather4<<<gblocks, 256, 0, stream>>>(base, (const long long*)payload,
                                               (const uint2*)y, (float*)d_out, N);
    } else {
        k_permute_pack<<<blocks_e, 256, 0, stream>>>(dst, src, t, cursor, payload, E);
        k_gather_fb<<<4096, 256, 0, stream>>>(base, payload, x_src, W, (float*)d_out, N);
    }
}

// Round 14
// 167.107 us; speedup vs baseline: 1.8559x; 1.8559x over previous
//
#include <hip/hip_runtime.h>
#include <math.h>

#define H 64
#define NXCD 8
#define CH 2048
#define CH2 8192
#define CAP 4096

typedef __attribute__((ext_vector_type(8))) short short8;
typedef __attribute__((ext_vector_type(4))) float f32x4;

__device__ inline ushort f2bf(float f) {
    union { float f; unsigned u; } v;
    v.f = f;
    unsigned r = v.u + 0x7FFFu + ((v.u >> 16) & 1u);
    return (ushort)(r >> 16);
}

// ---------- Pass 1: histogram of destinations ----------
__global__ void k_hist(const int* __restrict__ dst, unsigned* __restrict__ cnt, int E) {
    int i = blockIdx.x * blockDim.x + threadIdx.x;
    int st = gridDim.x * blockDim.x;
    int E4 = E >> 2;
    const int4* d4 = (const int4*)dst;
    for (int k = i; k < E4; k += st) {
        int4 v = d4[k];
        atomicAdd(&cnt[v.x], 1u);
        atomicAdd(&cnt[v.y], 1u);
        atomicAdd(&cnt[v.z], 1u);
        atomicAdd(&cnt[v.w], 1u);
    }
    for (int k = (E4 << 2) + i; k < E; k += st) atomicAdd(&cnt[dst[k]], 1u);
}

// ---------- Hierarchical exclusive scan ----------
__global__ __launch_bounds__(1024) void k_scanA(const unsigned* __restrict__ cnt,
                                                unsigned* __restrict__ base,
                                                unsigned* __restrict__ bsum, int N) {
    __shared__ unsigned wsum[16];
    int i = blockIdx.x * 1024 + threadIdx.x;
    unsigned v = (i < N) ? cnt[i] : 0u;
    int lane = threadIdx.x & 63, w = threadIdx.x >> 6;
    unsigned x = v;
#pragma unroll
    for (int off = 1; off < 64; off <<= 1) {
        unsigned y = __shfl_up(x, off, 64);
        if (lane >= off) x += y;
    }
    if (lane == 63) wsum[w] = x;
    __syncthreads();
    if (threadIdx.x < 16) {
        unsigned s = wsum[threadIdx.x];
#pragma unroll
        for (int off = 1; off < 16; off <<= 1) {
            unsigned y = __shfl_up(s, off, 16);
            if ((threadIdx.x & 15) >= off) s += y;
        }
        wsum[threadIdx.x] = s;
    }
    __syncthreads();
    unsigned wbase = (w > 0) ? wsum[w - 1] : 0u;
    if (i < N) base[i] = wbase + x - v;
    if (threadIdx.x == 1023) bsum[blockIdx.x] = wsum[15];
}

__global__ __launch_bounds__(1024) void k_scanB(const unsigned* __restrict__ bsum,
                                                unsigned* __restrict__ boff, int nb) {
    __shared__ unsigned wsum[16];
    int i = threadIdx.x;
    unsigned v = (i < nb) ? bsum[i] : 0u;
    int lane = i & 63, w = i >> 6;
    unsigned x = v;
#pragma unroll
    for (int off = 1; off < 64; off <<= 1) {
        unsigned y = __shfl_up(x, off, 64);
        if (lane >= off) x += y;
    }
    if (lane == 63) wsum[w] = x;
    __syncthreads();
    if (i < 16) {
        unsigned s = wsum[i];
#pragma unroll
        for (int off = 1; off < 16; off <<= 1) {
            unsigned y = __shfl_up(s, off, 16);
            if ((i & 15) >= off) s += y;
        }
        wsum[i] = s;
    }
    __syncthreads();
    unsigned wbase = (w > 0) ? wsum[w - 1] : 0u;
    if (i < nb) boff[i] = wbase + x - v;
}

__global__ void k_scanC(unsigned* __restrict__ base, unsigned* __restrict__ cursor,
                        const unsigned* __restrict__ boff, int N, int E) {
    int i = blockIdx.x * blockDim.x + threadIdx.x;
    int st = gridDim.x * blockDim.x;
    for (; i < N; i += st) {
        unsigned b = base[i] + boff[i >> 10];
        base[i] = b;
        cursor[i] = b;
    }
    if (blockIdx.x == 0 && threadIdx.x == 0) base[N] = (unsigned)E;
}

// ---------- meta init: bmeta[0..8]=part starts, bmeta[16..23]=part cursors ----------
__global__ void k_binit(const unsigned* __restrict__ base, unsigned* __restrict__ bmeta,
                        int N, int partsize) {
    int p = threadIdx.x;
    if (p <= NXCD) {
        int lo = p * partsize;
        if (lo > N) lo = N;
        unsigned b = base[lo];
        bmeta[p] = b;
        if (p < NXCD) bmeta[16 + p] = b;
    }
}

// ---------- bucket cursor init: bcur2[b] = base[min(b*256, N)] ----------
__global__ void k_binit2(const unsigned* __restrict__ base, unsigned* __restrict__ bcur2,
                         int N, int NB) {
    int b = threadIdx.x + blockIdx.x * blockDim.x;
    if (b <= NB) {
        int lo = b << 8;
        if (lo > N) lo = N;
        bcur2[b] = base[lo];
    }
}

// ---------- Pass 2a: edges -> part-binned u64 (d:17|src:17|ebf16) ----------
__global__ __launch_bounds__(256) void k_bin(const int* __restrict__ dst,
                                             const int* __restrict__ src,
                                             const float* __restrict__ t,
                                             unsigned* __restrict__ bcur,
                                             unsigned long long* __restrict__ bin1,
                                             int E, int partsize) {
    __shared__ unsigned lcnt[NXCD];
    __shared__ unsigned lofs[NXCD];
    int e0 = blockIdx.x * CH;
    int e1 = min(e0 + CH, E);
    if (threadIdx.x < NXCD) lcnt[threadIdx.x] = 0;
    __syncthreads();
    for (int i = e0 + threadIdx.x; i < e1; i += 256) {
        int d = dst[i];
        int p = 0;
#pragma unroll
        for (int k = 1; k < NXCD; ++k) p += (d >= k * partsize);
        atomicAdd(&lcnt[p], 1u);
    }
    __syncthreads();
    if (threadIdx.x < NXCD)
        lofs[threadIdx.x] = atomicAdd(&bcur[threadIdx.x], lcnt[threadIdx.x]);
    __syncthreads();
    const float inv = 1.0f / (0.5f + 1e-8f);
    for (int i = e0 + threadIdx.x; i < e1; i += 256) {
        int d = dst[i];
        int p = 0;
#pragma unroll
        for (int k = 1; k < NXCD; ++k) p += (d >= k * partsize);
        unsigned u = atomicAdd(&lofs[p], 1u);
        unsigned eb = f2bf(__expf(t[i] * inv));
        bin1[u] = ((unsigned long long)d << 33) | ((unsigned long long)src[i] << 16)
                | (unsigned long long)eb;
    }
}

// ---------- Pass 2b: part bin -> bucket bin (256-dst buckets, ~170-entry runs) ----------
// grid: (chunks, NXCD). Grid-strided over the part bin for distribution robustness.
__global__ __launch_bounds__(256) void k_bin2(const unsigned* __restrict__ bmeta,
                                              const unsigned long long* __restrict__ bin1,
                                              unsigned* __restrict__ bcur2,
                                              unsigned long long* __restrict__ bin2,
                                              int partsize) {
    __shared__ unsigned lcnt[64];
    __shared__ unsigned lofs[64];
    int p = blockIdx.y;
    int b0 = (int)bmeta[p], b1 = (int)bmeta[p + 1];
    int bloc0 = (p * partsize) >> 8;
    int stridec = gridDim.x * CH2;
    for (int c0 = b0 + blockIdx.x * CH2; c0 < b1; c0 += stridec) {
        int c1 = min(c0 + CH2, b1);
        if (threadIdx.x < 64) lcnt[threadIdx.x] = 0;
        __syncthreads();
        for (int i = c0 + threadIdx.x; i < c1; i += 256) {
            int d = (int)(bin1[i] >> 33);
            atomicAdd(&lcnt[(d >> 8) - bloc0], 1u);
        }
        __syncthreads();
        if (threadIdx.x < 64) {
            unsigned cn = lcnt[threadIdx.x];
            lofs[threadIdx.x] = cn ? atomicAdd(&bcur2[bloc0 + threadIdx.x], cn) : 0u;
        }
        __syncthreads();
        for (int i = c0 + threadIdx.x; i < c1; i += 256) {
            unsigned long long u = bin1[i];
            int d = (int)(u >> 33);
            unsigned pos = atomicAdd(&lofs[(d >> 8) - bloc0], 1u);
            bin2[pos] = u;
        }
        __syncthreads();
    }
}

// ---------- Pass 2c: bucket bin -> exact CSR payload via LDS assembly ----------
// One block per 256-dst bucket. Only sequential global reads + coalesced writes.
__global__ __launch_bounds__(256) void k_fine(const unsigned* __restrict__ base,
                                              const unsigned long long* __restrict__ bin2,
                                              int2* __restrict__ payload, int N) {
    __shared__ int2 sPay[CAP];
    __shared__ unsigned lrel[256];
    __shared__ unsigned lcur[256];
    int d0 = blockIdx.x << 8;
    int d1 = min(d0 + 256, N);
    int nd = d1 - d0;
    unsigned g0 = base[d0];
    unsigned g1 = base[d1];
    int cnt = (int)(g1 - g0);
    if (threadIdx.x < nd) {
        lrel[threadIdx.x] = base[d0 + threadIdx.x] - g0;
        lcur[threadIdx.x] = 0;
    }
    __syncthreads();
    for (int i = (int)g0 + threadIdx.x; i < (int)g1; i += 256) {
        unsigned long long u = bin2[i];
        int d = (int)(u >> 33);
        int s = (int)((u >> 16) & 0x1FFFF);
        float e = __uint_as_float((unsigned)(u & 0xFFFFu) << 16);
        int li = d - d0;
        unsigned lpos = lrel[li] + atomicAdd(&lcur[li], 1u);
        int2 v = make_int2(s, __float_as_int(e));
        if (lpos < CAP) sPay[lpos] = v;
        else payload[g0 + lpos] = v;  // spill: correctness only, ~never taken
    }
    __syncthreads();
    int wn = min(cnt, CAP);
    for (int j = threadIdx.x; j < wn; j += 256) payload[g0 + j] = sPay[j];
}

// ---------- Fallback permutes (R10-proven) ----------
__global__ void k_permute_part(const int* __restrict__ dst, const int* __restrict__ src,
                               const float* __restrict__ t, unsigned* __restrict__ cursor,
                               int2* __restrict__ payload, int E, int N) {
    const float inv = 1.0f / (0.5f + 1e-8f);
    int part = blockIdx.x & (NXCD - 1);
    int nslice = gridDim.x >> 3;
    int sblk = blockIdx.x >> 3;
    int lo = (int)((long long)part * N / NXCD);
    int hi = (int)((long long)(part + 1) * N / NXCD);
    int e0 = (int)((long long)sblk * E / nslice);
    int e1 = (int)((long long)(sblk + 1) * E / nslice);
    for (int i = e0 + threadIdx.x; i < e1; i += blockDim.x) {
        int d = dst[i];
        if (d >= lo && d < hi) {
            unsigned pos = atomicAdd(&cursor[d], 1u);
            float e = __expf(t[i] * inv);
            payload[pos] = make_int2(src[i], __float_as_int(e));
        }
    }
}

__global__ void k_permute_pack(const int* __restrict__ dst, const int* __restrict__ src,
                               const float* __restrict__ t, unsigned* __restrict__ cursor,
                               int2* __restrict__ payload, int E) {
    const float inv = 1.0f / (0.5f + 1e-8f);
    int i = blockIdx.x * blockDim.x + threadIdx.x;
    int st = gridDim.x * blockDim.x;
    for (; i < E; i += st) {
        unsigned pos = atomicAdd(&cursor[dst[i]], 1u);
        float e = __expf(t[i] * inv);
        payload[pos] = make_int2(src[i], __float_as_int(e));
    }
}

// ---------- Pre-transform: y(bf16) = x @ W^T via MFMA (verified R8) ----------
__global__ __launch_bounds__(256) void k_xform_mfma(const float* __restrict__ x,
                                                    const float* __restrict__ W,
                                                    ushort* __restrict__ y, int M) {
    int wid = (blockIdx.x * blockDim.x + threadIdx.x) >> 6;
    int lane = threadIdx.x & 63;
    int n0 = wid * 16;
    if (n0 >= M) return;
    int r = lane & 15, g = lane >> 4;

    short8 bfrag[4][2];
#pragma unroll
    for (int ct = 0; ct < 4; ++ct) {
#pragma unroll
        for (int kh = 0; kh < 2; ++kh) {
            const float* wp = &W[(size_t)(ct * 16 + r) * 64 + kh * 32 + g * 8];
            float4 w0 = *(const float4*)wp;
            float4 w1 = *(const float4*)(wp + 4);
            short8 bf;
            bf[0] = (short)f2bf(w0.x); bf[1] = (short)f2bf(w0.y);
            bf[2] = (short)f2bf(w0.z); bf[3] = (short)f2bf(w0.w);
            bf[4] = (short)f2bf(w1.x); bf[5] = (short)f2bf(w1.y);
            bf[6] = (short)f2bf(w1.z); bf[7] = (short)f2bf(w1.w);
            bfrag[ct][kh] = bf;
        }
    }
    int xr = n0 + r;
    if (xr >= M) xr = M - 1;
    const float* xp = &x[(size_t)xr * 64 + g * 8];
    short8 afrag[2];
#pragma unroll
    for (int kh = 0; kh < 2; ++kh) {
        float4 a0 = *(const float4*)(xp + kh * 32);
        float4 a1 = *(const float4*)(xp + kh * 32 + 4);
        short8 af;
        af[0] = (short)f2bf(a0.x); af[1] = (short)f2bf(a0.y);
        af[2] = (short)f2bf(a0.z); af[3] = (short)f2bf(a0.w);
        af[4] = (short)f2bf(a1.x); af[5] = (short)f2bf(a1.y);
        af[6] = (short)f2bf(a1.z); af[7] = (short)f2bf(a1.w);
        afrag[kh] = af;
    }
#pragma unroll
    for (int ct = 0; ct < 4; ++ct) {
        f32x4 acc = {0.f, 0.f, 0.f, 0.f};
        acc = __builtin_amdgcn_mfma_f32_16x16x32_bf16(afrag[0], bfrag[ct][0], acc, 0, 0, 0);
        acc = __builtin_amdgcn_mfma_f32_16x16x32_bf16(afrag[1], bfrag[ct][1], acc, 0, 0, 0);
#pragma unroll
        for (int q = 0; q < 4; ++q) {
            int row = n0 + g * 4 + q;
            if (row < M) y[(size_t)row * 64 + ct * 16 + r] = f2bf(acc[q]);
        }
    }
}

// ---------- Pass 3: weighted gather, 4 dests/wave, 16 lanes/dest (verified R10) ----------
__global__ __launch_bounds__(256) void k_gather4(const unsigned* __restrict__ base,
                                                 const long long* __restrict__ payload,
                                                 const uint2* __restrict__ y2,
                                                 float* __restrict__ out, int N) {
    int tid = blockIdx.x * blockDim.x + threadIdx.x;
    int lane = threadIdx.x & 63;
    int g = lane >> 4, f = lane & 15;
    int d = (tid >> 6) * 4 + g;
    if (d >= N) return;
    unsigned r0 = base[d], r1 = base[d + 1];
    int deg = (int)(r1 - r0);
    float acc0 = 0.f, acc1 = 0.f, acc2 = 0.f, acc3 = 0.f, ssum = 0.f;
    for (int it = 0; it < deg; it += 4) {
        float e[4];
        int s[4];
#pragma unroll
        for (int k2 = 0; k2 < 4; ++k2) {
            long long pl = __builtin_nontemporal_load(&payload[r0 + it + k2]);
            bool ok = (it + k2) < deg;
            e[k2] = ok ? __int_as_float((int)(pl >> 32)) : 0.f;
            s[k2] = ok ? (int)(pl & 0xFFFFFFFFll) : 0;
            ssum += e[k2];
        }
        uint2 v[4];
#pragma unroll
        for (int k2 = 0; k2 < 4; ++k2) v[k2] = y2[(size_t)s[k2] * 16 + f];
#pragma unroll
        for (int k2 = 0; k2 < 4; ++k2) {
            float x0 = __uint_as_float(v[k2].x << 16);
            float x1 = __uint_as_float(v[k2].x & 0xFFFF0000u);
            float x2 = __uint_as_float(v[k2].y << 16);
            float x3 = __uint_as_float(v[k2].y & 0xFFFF0000u);
            acc0 = fmaf(e[k2], x0, acc0);
            acc1 = fmaf(e[k2], x1, acc1);
            acc2 = fmaf(e[k2], x2, acc2);
            acc3 = fmaf(e[k2], x3, acc3);
        }
    }
    float rs = 1.0f / (ssum + 1e-16f);
    f32x4 o = {acc0 * rs, acc1 * rs, acc2 * rs, acc3 * rs};
    __builtin_nontemporal_store(o, (f32x4*)&out[(size_t)d * H + f * 4]);
}

// ---------- Fallback gather (verified R3/R5) ----------
__global__ __launch_bounds__(256) void k_gather_fb(const unsigned* __restrict__ base,
                                                   const int2* __restrict__ payload,
                                                   const float* __restrict__ x_src,
                                                   const float* __restrict__ W,
                                                   float* __restrict__ out, int N) {
    __shared__ float wt[H * H];
    for (int idx = threadIdx.x; idx < H * H; idx += blockDim.x) {
        int j = idx >> 6, k = idx & 63;
        wt[k * H + j] = W[idx];
    }
    __syncthreads();
    int lane = threadIdx.x & 63;
    int wid = (blockIdx.x * blockDim.x + threadIdx.x) >> 6;
    int nw = (gridDim.x * blockDim.x) >> 6;
    for (int d = wid; d < N; d += nw) {
        unsigned r0 = base[d], r1 = base[d + 1];
        int deg = (int)(r1 - r0);
        float acc = 0.0f, ssum = 0.0f;
        for (int c = 0; c < deg; c += 64) {
            int j = c + lane;
            int cd = min(64, deg - c);
            float e = 0.0f;
            int sidx = 0;
            if (j < deg) {
                int2 p = payload[r0 + j];
                sidx = p.x;
                e = __int_as_float(p.y);
            }
            float cs = e;
#pragma unroll
            for (int off = 32; off >= 1; off >>= 1) cs += __shfl_xor(cs, off, 64);
            ssum += cs;
            for (int q = 0; q < cd; q += 8) {
                float a[8];
                int sv[8];
                float v[8];
#pragma unroll
                for (int u = 0; u < 8; ++u) {
                    a[u] = __shfl(e, q + u, 64);
                    sv[u] = __shfl(sidx, q + u, 64);
                }
#pragma unroll
                for (int u = 0; u < 8; ++u) v[u] = x_src[(size_t)sv[u] * H + lane];
#pragma unroll
                for (int u = 0; u < 8; ++u) acc = fmaf(a[u], v[u], acc);
            }
        }
        acc *= 1.0f / (ssum + 1e-16f);
        float o = 0.0f;
#pragma unroll
        for (int k = 0; k < H; ++k) o = fmaf(__shfl(acc, k, 64), wt[k * H + lane], o);
        out[(size_t)d * H + lane] = o;
    }
}

extern "C" void kernel_launch(void* const* d_in, const int* in_sizes, int n_in,
                              void* d_out, int out_size, void* d_ws, size_t ws_size,
                              hipStream_t stream) {
    const float* x_src = (const float*)d_in[0];
    const float* W = (const float*)d_in[2];
    const int* edge_index = (const int*)d_in[3];
    const float* t = (const float*)d_in[4];

    int E = in_sizes[4];
    int N = in_sizes[1] / H;  // N_DST
    int M = in_sizes[0] / H;  // N_SRC
    const int* src = edge_index;
    const int* dst = edge_index + E;

    // ws layout: base[N+1] | cursor[N] | bsum[1024] | boff[1024] | bmeta[32] | bcur2[NB+1≤1024]
    //            | payload int2[E] (aliased as bin1 u64[E]) | bin2 u64[E] | y bf16[M*H]
    unsigned* base = (unsigned*)d_ws;
    unsigned* cursor = base + (size_t)N + 1;
    unsigned* bsum = cursor + N;
    unsigned* boff = bsum + 1024;
    unsigned* bmeta = boff + 1024;
    unsigned* bcur2 = bmeta + 32;
    size_t pay_off = (((size_t)(2 * N + 3105)) * 4 + 15) & ~(size_t)15;
    int2* payload = (int2*)((char*)d_ws + pay_off);
    unsigned long long* bin1 = (unsigned long long*)payload;  // alias (dead before k_fine writes)
    size_t b2_off = (pay_off + (size_t)E * 8 + 15) & ~(size_t)15;
    unsigned long long* bin2 = (unsigned long long*)((char*)d_ws + b2_off);
    size_t y_off = b2_off + (size_t)E * 8;
    ushort* y = (ushort*)((char*)d_ws + y_off);

    bool have_payload = (ws_size >= pay_off + (size_t)E * 8 + 32);
    bool have_y_small = (ws_size >= pay_off + (size_t)E * 8 + (size_t)M * H * 2 + 32);
    bool have_full = (ws_size >= y_off + (size_t)M * H * 2);
    bool packable = (M < (1 << 17)) && (N < (1 << 17));

    int nb = (N + 1023) / 1024;
    int ps0 = (N + NXCD - 1) / NXCD;
    int partsize = (ps0 + 255) & ~255;  // 256-aligned so buckets nest in parts
    int NB = (N + 255) >> 8;

    hipMemsetAsync(cursor, 0, (size_t)N * sizeof(unsigned), stream);

    int blocks_e = (E + 255) / 256;
    if (blocks_e > 2048) blocks_e = 2048;

    k_hist<<<1024, 256, 0, stream>>>(dst, cursor, E);
    k_scanA<<<nb, 1024, 0, stream>>>(cursor, base, bsum, N);
    k_scanB<<<1, 1024, 0, stream>>>(bsum, boff, nb);
    k_scanC<<<512, 256, 0, stream>>>(base, cursor, boff, N, E);

    if (have_full && packable) {
        int xblocks = ((M + 15) / 16 * 64 + 255) / 256;
        k_xform_mfma<<<xblocks, 256, 0, stream>>>(x_src, W, y, M);
        k_binit<<<1, 16, 0, stream>>>(base, bmeta, N, partsize);
        k_binit2<<<(NB + 512) / 512, 512, 0, stream>>>(base, bcur2, N, NB);
        int nbin = (E + CH - 1) / CH;
        k_bin<<<nbin, 256, 0, stream>>>(dst, src, t, bmeta + 16, bin1, E, partsize);
        int nb2 = (E / NXCD + CH2 - 1) / CH2 + 1;
        dim3 g2(nb2, NXCD);
        k_bin2<<<g2, 256, 0, stream>>>(bmeta, bin1, bcur2, bin2, partsize);
        k_fine<<<NB, 256, 0, stream>>>(base, bin2, payload, N);
        int gblocks = (N + 15) / 16;
        k_gather4<<<gblocks, 256, 0, stream>>>(base, (const long long*)payload,
                                               (const uint2*)y, (float*)d_out, N);
    } else if (have_y_small) {
        // R10 path: y placed right after payload
        ushort* y2p = (ushort*)((char*)d_ws + pay_off + (size_t)E * 8);
        int xblocks = ((M + 15) / 16 * 64 + 255) / 256;
        k_xform_mfma<<<xblocks, 256, 0, stream>>>(x_src, W, y2p, M);
        k_permute_part<<<2048, 256, 0, stream>>>(dst, src, t, cursor, payload, E, N);
        int gblocks = (N + 15) / 16;
        k_gather4<<<gblocks, 256, 0, stream>>>(base, (const long long*)payload,
                                               (const uint2*)y2p, (float*)d_out, N);
    } else {
        k_permute_pack<<<blocks_e, 256, 0, stream>>>(dst, src, t, cursor, payload, E);
        k_gather_fb<<<4096, 256, 0, stream>>>(base, payload, x_src, W, (float*)d_out, N);
    }
}

// Round 15
// 143.446 us; speedup vs baseline: 2.1620x; 1.1649x over previous
//
#include <hip/hip_runtime.h>
#include <math.h>

#define H 64
#define NXCD 8
#define CH 2048
#define CH2 8192
#define CAP 4096

typedef __attribute__((ext_vector_type(8))) short short8;
typedef __attribute__((ext_vector_type(4))) float f32x4;

__device__ inline ushort f2bf(float f) {
    union { float f; unsigned u; } v;
    v.f = f;
    unsigned r = v.u + 0x7FFFu + ((v.u >> 16) & 1u);
    return (ushort)(r >> 16);
}

// ================= FAST PATH =================

// ---------- Stage 0: bucket-level histogram via LDS (no random global atomics) ----------
__global__ __launch_bounds__(256) void k_count(const int* __restrict__ dst,
                                               unsigned* __restrict__ bcnt, int E, int NB) {
    __shared__ unsigned lc[1024];
    for (int j = threadIdx.x; j < NB; j += 256) lc[j] = 0;
    __syncthreads();
    int i = blockIdx.x * blockDim.x + threadIdx.x;
    int st = gridDim.x * blockDim.x;
    int E4 = E >> 2;
    const int4* d4 = (const int4*)dst;
    for (int k = i; k < E4; k += st) {
        int4 v = d4[k];
        atomicAdd(&lc[v.x >> 8], 1u);
        atomicAdd(&lc[v.y >> 8], 1u);
        atomicAdd(&lc[v.z >> 8], 1u);
        atomicAdd(&lc[v.w >> 8], 1u);
    }
    for (int k = (E4 << 2) + i; k < E; k += st) atomicAdd(&lc[dst[k] >> 8], 1u);
    __syncthreads();
    for (int j = threadIdx.x; j < NB; j += 256)
        if (lc[j]) atomicAdd(&bcnt[j], lc[j]);
}

// ---------- Stage 1: single-block scan of bucket counts -> starts, cursors, part meta ----------
__global__ __launch_bounds__(1024) void k_scan_small(const unsigned* __restrict__ bcnt,
                                                     unsigned* __restrict__ bstart2,
                                                     unsigned* __restrict__ bcur2,
                                                     unsigned* __restrict__ bmeta,
                                                     int NB, int partsize, int E) {
    __shared__ unsigned wsum[16];
    __shared__ unsigned sex[1025];
    int i = threadIdx.x;
    unsigned v = (i < NB) ? bcnt[i] : 0u;
    int lane = i & 63, w = i >> 6;
    unsigned x = v;
#pragma unroll
    for (int off = 1; off < 64; off <<= 1) {
        unsigned y = __shfl_up(x, off, 64);
        if (lane >= off) x += y;
    }
    if (lane == 63) wsum[w] = x;
    __syncthreads();
    if (i < 16) {
        unsigned s = wsum[i];
#pragma unroll
        for (int off = 1; off < 16; off <<= 1) {
            unsigned y = __shfl_up(s, off, 16);
            if ((i & 15) >= off) s += y;
        }
        wsum[i] = s;
    }
    __syncthreads();
    unsigned wbase = (w > 0) ? wsum[w - 1] : 0u;
    unsigned excl = wbase + x - v;
    sex[i] = excl;
    if (i == 0) sex[1024] = (unsigned)E;
    __syncthreads();
    if (i <= NB) bstart2[i] = sex[i];
    if (i < NB) bcur2[i] = sex[i];
    if (i <= NXCD) {
        int bidx = (i * partsize) >> 8;
        if (bidx > NB) bidx = NB;
        bmeta[i] = sex[bidx];
        if (i < NXCD) bmeta[16 + i] = sex[bidx];
    }
}

// ---------- Stage 2a: edges -> part-binned u64 (d:17|src:17|ebf16) (verified R14) ----------
__global__ __launch_bounds__(256) void k_bin(const int* __restrict__ dst,
                                             const int* __restrict__ src,
                                             const float* __restrict__ t,
                                             unsigned* __restrict__ bcur,
                                             unsigned long long* __restrict__ bin1,
                                             int E, int partsize) {
    __shared__ unsigned lcnt[NXCD];
    __shared__ unsigned lofs[NXCD];
    int e0 = blockIdx.x * CH;
    int e1 = min(e0 + CH, E);
    if (threadIdx.x < NXCD) lcnt[threadIdx.x] = 0;
    __syncthreads();
    for (int i = e0 + threadIdx.x; i < e1; i += 256) {
        int d = dst[i];
        int p = 0;
#pragma unroll
        for (int k = 1; k < NXCD; ++k) p += (d >= k * partsize);
        atomicAdd(&lcnt[p], 1u);
    }
    __syncthreads();
    if (threadIdx.x < NXCD)
        lofs[threadIdx.x] = atomicAdd(&bcur[threadIdx.x], lcnt[threadIdx.x]);
    __syncthreads();
    const float inv = 1.0f / (0.5f + 1e-8f);
    for (int i = e0 + threadIdx.x; i < e1; i += 256) {
        int d = dst[i];
        int p = 0;
#pragma unroll
        for (int k = 1; k < NXCD; ++k) p += (d >= k * partsize);
        unsigned u = atomicAdd(&lofs[p], 1u);
        unsigned eb = f2bf(__expf(t[i] * inv));
        bin1[u] = ((unsigned long long)d << 33) | ((unsigned long long)src[i] << 16)
                | (unsigned long long)eb;
    }
}

// ---------- Stage 2b: part bin -> bucket bin (verified R14) ----------
__global__ __launch_bounds__(256) void k_bin2(const unsigned* __restrict__ bmeta,
                                              const unsigned long long* __restrict__ bin1,
                                              unsigned* __restrict__ bcur2,
                                              unsigned long long* __restrict__ bin2,
                                              int partsize) {
    __shared__ unsigned lcnt[64];
    __shared__ unsigned lofs[64];
    int p = blockIdx.y;
    int b0 = (int)bmeta[p], b1 = (int)bmeta[p + 1];
    int bloc0 = (p * partsize) >> 8;
    int stridec = gridDim.x * CH2;
    for (int c0 = b0 + blockIdx.x * CH2; c0 < b1; c0 += stridec) {
        int c1 = min(c0 + CH2, b1);
        if (threadIdx.x < 64) lcnt[threadIdx.x] = 0;
        __syncthreads();
        for (int i = c0 + threadIdx.x; i < c1; i += 256) {
            int d = (int)(bin1[i] >> 33);
            atomicAdd(&lcnt[(d >> 8) - bloc0], 1u);
        }
        __syncthreads();
        if (threadIdx.x < 64) {
            unsigned cn = lcnt[threadIdx.x];
            lofs[threadIdx.x] = cn ? atomicAdd(&bcur2[bloc0 + threadIdx.x], cn) : 0u;
        }
        __syncthreads();
        for (int i = c0 + threadIdx.x; i < c1; i += 256) {
            unsigned long long u = bin1[i];
            int d = (int)(u >> 33);
            unsigned pos = atomicAdd(&lofs[(d >> 8) - bloc0], 1u);
            bin2[pos] = u;
        }
        __syncthreads();
    }
}

// ---------- Stage 2c: bucket bin -> CSR payload + base[] via LDS hist+scan+assembly ----------
__global__ __launch_bounds__(256) void k_fine2(const unsigned* __restrict__ bstart2,
                                               const unsigned long long* __restrict__ bin2,
                                               int2* __restrict__ payload,
                                               unsigned* __restrict__ base, int N, int E) {
    __shared__ int2 sPay[CAP];
    __shared__ unsigned lcnt[256];
    __shared__ unsigned lrel[256];
    __shared__ unsigned wsum[4];
    int b = blockIdx.x;
    int d0 = b << 8;
    int d1 = min(d0 + 256, N);
    int nd = d1 - d0;
    unsigned g0 = bstart2[b];
    unsigned g1 = bstart2[b + 1];
    int cnt = (int)(g1 - g0);
    int tid = threadIdx.x;
    lcnt[tid] = 0;
    __syncthreads();
    // pass 1: count local dsts
    for (int i = (int)g0 + tid; i < (int)g1; i += 256)
        atomicAdd(&lcnt[(int)(bin2[i] >> 33) - d0], 1u);
    __syncthreads();
    // exclusive scan of 256 counters (4 waves)
    unsigned v = lcnt[tid];
    int lane = tid & 63, w = tid >> 6;
    unsigned x = v;
#pragma unroll
    for (int off = 1; off < 64; off <<= 1) {
        unsigned y = __shfl_up(x, off, 64);
        if (lane >= off) x += y;
    }
    if (lane == 63) wsum[w] = x;
    __syncthreads();
    if (tid == 0) {
        unsigned s = 0;
#pragma unroll
        for (int k = 0; k < 4; ++k) { unsigned tq = wsum[k]; wsum[k] = s; s += tq; }
    }
    __syncthreads();
    unsigned excl = wsum[w] + x - v;
    lrel[tid] = excl;
    // write base for this bucket (coalesced)
    if (tid < nd) base[d0 + tid] = g0 + excl;
    if (b == gridDim.x - 1 && tid == 0) base[N] = (unsigned)E;
    __syncthreads();
    lcnt[tid] = excl;  // becomes running cursor
    __syncthreads();
    // pass 2: scatter into LDS slab
    for (int i = (int)g0 + tid; i < (int)g1; i += 256) {
        unsigned long long u = bin2[i];
        int d = (int)(u >> 33);
        int s = (int)((u >> 16) & 0x1FFFF);
        float e = __uint_as_float((unsigned)(u & 0xFFFFu) << 16);
        unsigned lpos = atomicAdd(&lcnt[d - d0], 1u);
        int2 pv = make_int2(s, __float_as_int(e));
        if (lpos < CAP) sPay[lpos] = pv;
        else payload[g0 + lpos] = pv;  // spill: correctness only
    }
    __syncthreads();
    int wn = min(cnt, CAP);
    for (int j = tid; j < wn; j += 256) payload[g0 + j] = sPay[j];
}

// ---------- Pre-transform: y(bf16) = x @ W^T via MFMA (verified R8) ----------
__global__ __launch_bounds__(256) void k_xform_mfma(const float* __restrict__ x,
                                                    const float* __restrict__ W,
                                                    ushort* __restrict__ y, int M) {
    int wid = (blockIdx.x * blockDim.x + threadIdx.x) >> 6;
    int lane = threadIdx.x & 63;
    int n0 = wid * 16;
    if (n0 >= M) return;
    int r = lane & 15, g = lane >> 4;

    short8 bfrag[4][2];
#pragma unroll
    for (int ct = 0; ct < 4; ++ct) {
#pragma unroll
        for (int kh = 0; kh < 2; ++kh) {
            const float* wp = &W[(size_t)(ct * 16 + r) * 64 + kh * 32 + g * 8];
            float4 w0 = *(const float4*)wp;
            float4 w1 = *(const float4*)(wp + 4);
            short8 bf;
            bf[0] = (short)f2bf(w0.x); bf[1] = (short)f2bf(w0.y);
            bf[2] = (short)f2bf(w0.z); bf[3] = (short)f2bf(w0.w);
            bf[4] = (short)f2bf(w1.x); bf[5] = (short)f2bf(w1.y);
            bf[6] = (short)f2bf(w1.z); bf[7] = (short)f2bf(w1.w);
            bfrag[ct][kh] = bf;
        }
    }
    int xr = n0 + r;
    if (xr >= M) xr = M - 1;
    const float* xp = &x[(size_t)xr * 64 + g * 8];
    short8 afrag[2];
#pragma unroll
    for (int kh = 0; kh < 2; ++kh) {
        float4 a0 = *(const float4*)(xp + kh * 32);
        float4 a1 = *(const float4*)(xp + kh * 32 + 4);
        short8 af;
        af[0] = (short)f2bf(a0.x); af[1] = (short)f2bf(a0.y);
        af[2] = (short)f2bf(a0.z); af[3] = (short)f2bf(a0.w);
        af[4] = (short)f2bf(a1.x); af[5] = (short)f2bf(a1.y);
        af[6] = (short)f2bf(a1.z); af[7] = (short)f2bf(a1.w);
        afrag[kh] = af;
    }
#pragma unroll
    for (int ct = 0; ct < 4; ++ct) {
        f32x4 acc = {0.f, 0.f, 0.f, 0.f};
        acc = __builtin_amdgcn_mfma_f32_16x16x32_bf16(afrag[0], bfrag[ct][0], acc, 0, 0, 0);
        acc = __builtin_amdgcn_mfma_f32_16x16x32_bf16(afrag[1], bfrag[ct][1], acc, 0, 0, 0);
#pragma unroll
        for (int q = 0; q < 4; ++q) {
            int row = n0 + g * 4 + q;
            if (row < M) y[(size_t)row * 64 + ct * 16 + r] = f2bf(acc[q]);
        }
    }
}

// ---------- Pass 3: weighted gather, 4 dests/wave, 16 lanes/dest (verified R10) ----------
__global__ __launch_bounds__(256) void k_gather4(const unsigned* __restrict__ base,
                                                 const long long* __restrict__ payload,
                                                 const uint2* __restrict__ y2,
                                                 float* __restrict__ out, int N) {
    int tid = blockIdx.x * blockDim.x + threadIdx.x;
    int lane = threadIdx.x & 63;
    int g = lane >> 4, f = lane & 15;
    int d = (tid >> 6) * 4 + g;
    if (d >= N) return;
    unsigned r0 = base[d], r1 = base[d + 1];
    int deg = (int)(r1 - r0);
    float acc0 = 0.f, acc1 = 0.f, acc2 = 0.f, acc3 = 0.f, ssum = 0.f;
    for (int it = 0; it < deg; it += 4) {
        float e[4];
        int s[4];
#pragma unroll
        for (int k2 = 0; k2 < 4; ++k2) {
            long long pl = __builtin_nontemporal_load(&payload[r0 + it + k2]);
            bool ok = (it + k2) < deg;
            e[k2] = ok ? __int_as_float((int)(pl >> 32)) : 0.f;
            s[k2] = ok ? (int)(pl & 0xFFFFFFFFll) : 0;
            ssum += e[k2];
        }
        uint2 v[4];
#pragma unroll
        for (int k2 = 0; k2 < 4; ++k2) v[k2] = y2[(size_t)s[k2] * 16 + f];
#pragma unroll
        for (int k2 = 0; k2 < 4; ++k2) {
            float x0 = __uint_as_float(v[k2].x << 16);
            float x1 = __uint_as_float(v[k2].x & 0xFFFF0000u);
            float x2 = __uint_as_float(v[k2].y << 16);
            float x3 = __uint_as_float(v[k2].y & 0xFFFF0000u);
            acc0 = fmaf(e[k2], x0, acc0);
            acc1 = fmaf(e[k2], x1, acc1);
            acc2 = fmaf(e[k2], x2, acc2);
            acc3 = fmaf(e[k2], x3, acc3);
        }
    }
    float rs = 1.0f / (ssum + 1e-16f);
    f32x4 o = {acc0 * rs, acc1 * rs, acc2 * rs, acc3 * rs};
    __builtin_nontemporal_store(o, (f32x4*)&out[(size_t)d * H + f * 4]);
}

// ================= FALLBACK PATH (R10-proven) =================

__global__ void k_hist(const int* __restrict__ dst, unsigned* __restrict__ cnt, int E) {
    int i = blockIdx.x * blockDim.x + threadIdx.x;
    int st = gridDim.x * blockDim.x;
    int E4 = E >> 2;
    const int4* d4 = (const int4*)dst;
    for (int k = i; k < E4; k += st) {
        int4 v = d4[k];
        atomicAdd(&cnt[v.x], 1u);
        atomicAdd(&cnt[v.y], 1u);
        atomicAdd(&cnt[v.z], 1u);
        atomicAdd(&cnt[v.w], 1u);
    }
    for (int k = (E4 << 2) + i; k < E; k += st) atomicAdd(&cnt[dst[k]], 1u);
}

__global__ __launch_bounds__(1024) void k_scanA(const unsigned* __restrict__ cnt,
                                                unsigned* __restrict__ base,
                                                unsigned* __restrict__ bsum, int N) {
    __shared__ unsigned wsum[16];
    int i = blockIdx.x * 1024 + threadIdx.x;
    unsigned v = (i < N) ? cnt[i] : 0u;
    int lane = threadIdx.x & 63, w = threadIdx.x >> 6;
    unsigned x = v;
#pragma unroll
    for (int off = 1; off < 64; off <<= 1) {
        unsigned y = __shfl_up(x, off, 64);
        if (lane >= off) x += y;
    }
    if (lane == 63) wsum[w] = x;
    __syncthreads();
    if (threadIdx.x < 16) {
        unsigned s = wsum[threadIdx.x];
#pragma unroll
        for (int off = 1; off < 16; off <<= 1) {
            unsigned y = __shfl_up(s, off, 16);
            if ((threadIdx.x & 15) >= off) s += y;
        }
        wsum[threadIdx.x] = s;
    }
    __syncthreads();
    unsigned wbase = (w > 0) ? wsum[w - 1] : 0u;
    if (i < N) base[i] = wbase + x - v;
    if (threadIdx.x == 1023) bsum[blockIdx.x] = wsum[15];
}

__global__ __launch_bounds__(1024) void k_scanB(const unsigned* __restrict__ bsum,
                                                unsigned* __restrict__ boff, int nb) {
    __shared__ unsigned wsum[16];
    int i = threadIdx.x;
    unsigned v = (i < nb) ? bsum[i] : 0u;
    int lane = i & 63, w = i >> 6;
    unsigned x = v;
#pragma unroll
    for (int off = 1; off < 64; off <<= 1) {
        unsigned y = __shfl_up(x, off, 64);
        if (lane >= off) x += y;
    }
    if (lane == 63) wsum[w] = x;
    __syncthreads();
    if (i < 16) {
        unsigned s = wsum[i];
#pragma unroll
        for (int off = 1; off < 16; off <<= 1) {
            unsigned y = __shfl_up(s, off, 16);
            if ((i & 15) >= off) s += y;
        }
        wsum[i] = s;
    }
    __syncthreads();
    unsigned wbase = (w > 0) ? wsum[w - 1] : 0u;
    if (i < nb) boff[i] = wbase + x - v;
}

__global__ void k_scanC(unsigned* __restrict__ base, unsigned* __restrict__ cursor,
                        const unsigned* __restrict__ boff, int N, int E) {
    int i = blockIdx.x * blockDim.x + threadIdx.x;
    int st = gridDim.x * blockDim.x;
    for (; i < N; i += st) {
        unsigned b = base[i] + boff[i >> 10];
        base[i] = b;
        cursor[i] = b;
    }
    if (blockIdx.x == 0 && threadIdx.x == 0) base[N] = (unsigned)E;
}

__global__ void k_permute_part(const int* __restrict__ dst, const int* __restrict__ src,
                               const float* __restrict__ t, unsigned* __restrict__ cursor,
                               int2* __restrict__ payload, int E, int N) {
    const float inv = 1.0f / (0.5f + 1e-8f);
    int part = blockIdx.x & (NXCD - 1);
    int nslice = gridDim.x >> 3;
    int sblk = blockIdx.x >> 3;
    int lo = (int)((long long)part * N / NXCD);
    int hi = (int)((long long)(part + 1) * N / NXCD);
    int e0 = (int)((long long)sblk * E / nslice);
    int e1 = (int)((long long)(sblk + 1) * E / nslice);
    for (int i = e0 + threadIdx.x; i < e1; i += blockDim.x) {
        int d = dst[i];
        if (d >= lo && d < hi) {
            unsigned pos = atomicAdd(&cursor[d], 1u);
            float e = __expf(t[i] * inv);
            payload[pos] = make_int2(src[i], __float_as_int(e));
        }
    }
}

__global__ void k_permute_pack(const int* __restrict__ dst, const int* __restrict__ src,
                               const float* __restrict__ t, unsigned* __restrict__ cursor,
                               int2* __restrict__ payload, int E) {
    const float inv = 1.0f / (0.5f + 1e-8f);
    int i = blockIdx.x * blockDim.x + threadIdx.x;
    int st = gridDim.x * blockDim.x;
    for (; i < E; i += st) {
        unsigned pos = atomicAdd(&cursor[dst[i]], 1u);
        float e = __expf(t[i] * inv);
        payload[pos] = make_int2(src[i], __float_as_int(e));
    }
}

__global__ __launch_bounds__(256) void k_gather_fb(const unsigned* __restrict__ base,
                                                   const int2* __restrict__ payload,
                                                   const float* __restrict__ x_src,
                                                   const float* __restrict__ W,
                                                   float* __restrict__ out, int N) {
    __shared__ float wt[H * H];
    for (int idx = threadIdx.x; idx < H * H; idx += blockDim.x) {
        int j = idx >> 6, k = idx & 63;
        wt[k * H + j] = W[idx];
    }
    __syncthreads();
    int lane = threadIdx.x & 63;
    int wid = (blockIdx.x * blockDim.x + threadIdx.x) >> 6;
    int nw = (gridDim.x * blockDim.x) >> 6;
    for (int d = wid; d < N; d += nw) {
        unsigned r0 = base[d], r1 = base[d + 1];
        int deg = (int)(r1 - r0);
        float acc = 0.0f, ssum = 0.0f;
        for (int c = 0; c < deg; c += 64) {
            int j = c + lane;
            int cd = min(64, deg - c);
            float e = 0.0f;
            int sidx = 0;
            if (j < deg) {
                int2 p = payload[r0 + j];
                sidx = p.x;
                e = __int_as_float(p.y);
            }
            float cs = e;
#pragma unroll
            for (int off = 32; off >= 1; off >>= 1) cs += __shfl_xor(cs, off, 64);
            ssum += cs;
            for (int q = 0; q < cd; q += 8) {
                float a[8];
                int sv[8];
                float v[8];
#pragma unroll
                for (int u = 0; u < 8; ++u) {
                    a[u] = __shfl(e, q + u, 64);
                    sv[u] = __shfl(sidx, q + u, 64);
                }
#pragma unroll
                for (int u = 0; u < 8; ++u) v[u] = x_src[(size_t)sv[u] * H + lane];
#pragma unroll
                for (int u = 0; u < 8; ++u) acc = fmaf(a[u], v[u], acc);
            }
        }
        acc *= 1.0f / (ssum + 1e-16f);
        float o = 0.0f;
#pragma unroll
        for (int k = 0; k < H; ++k) o = fmaf(__shfl(acc, k, 64), wt[k * H + lane], o);
        out[(size_t)d * H + lane] = o;
    }
}

extern "C" void kernel_launch(void* const* d_in, const int* in_sizes, int n_in,
                              void* d_out, int out_size, void* d_ws, size_t ws_size,
                              hipStream_t stream) {
    const float* x_src = (const float*)d_in[0];
    const float* W = (const float*)d_in[2];
    const int* edge_index = (const int*)d_in[3];
    const float* t = (const float*)d_in[4];

    int E = in_sizes[4];
    int N = in_sizes[1] / H;  // N_DST
    int M = in_sizes[0] / H;  // N_SRC
    const int* src = edge_index;
    const int* dst = edge_index + E;

    // ws layout (u32): base[N+1] | cursor[N] | bsum[1024] | boff[1024] | bmeta[32]
    //                 | bcnt[1024] | bstart2[1056] | bcur2[1056]
    //                 | payload int2[E] (alias bin1 u64[E]) | bin2 u64[E] | y bf16[M*H]
    unsigned* base = (unsigned*)d_ws;
    unsigned* cursor = base + (size_t)N + 1;
    unsigned* bsum = cursor + N;
    unsigned* boff = bsum + 1024;
    unsigned* bmeta = boff + 1024;
    unsigned* bcnt = bmeta + 32;
    unsigned* bstart2 = bcnt + 1024;
    unsigned* bcur2 = bstart2 + 1056;
    size_t head_u32 = (size_t)(2 * N + 1) + 1024 + 1024 + 32 + 1024 + 1056 + 1056;
    size_t pay_off = (head_u32 * 4 + 15) & ~(size_t)15;
    int2* payload = (int2*)((char*)d_ws + pay_off);
    unsigned long long* bin1 = (unsigned long long*)payload;  // alias (dead before k_fine2 writes)
    size_t b2_off = (pay_off + (size_t)E * 8 + 15) & ~(size_t)15;
    unsigned long long* bin2 = (unsigned long long*)((char*)d_ws + b2_off);
    size_t y_off = b2_off + (size_t)E * 8;
    ushort* y = (ushort*)((char*)d_ws + y_off);

    bool have_payload = (ws_size >= pay_off + (size_t)E * 8 + 32);
    bool have_y_small = (ws_size >= pay_off + (size_t)E * 8 + (size_t)M * H * 2 + 32);
    bool have_full = (ws_size >= y_off + (size_t)M * H * 2);
    bool packable = (M < (1 << 17)) && (N < (1 << 17));

    int nb = (N + 1023) / 1024;
    int ps0 = (N + NXCD - 1) / NXCD;
    int partsize = (ps0 + 255) & ~255;  // 256-aligned so buckets nest in parts
    int NB = (N + 255) >> 8;

    int blocks_e = (E + 255) / 256;
    if (blocks_e > 2048) blocks_e = 2048;

    if (have_full && packable && NB <= 1024) {
        hipMemsetAsync(bcnt, 0, (size_t)NB * sizeof(unsigned), stream);
        int xblocks = ((M + 15) / 16 * 64 + 255) / 256;
        k_xform_mfma<<<xblocks, 256, 0, stream>>>(x_src, W, y, M);
        k_count<<<1024, 256, 0, stream>>>(dst, bcnt, E, NB);
        k_scan_small<<<1, 1024, 0, stream>>>(bcnt, bstart2, bcur2, bmeta, NB, partsize, E);
        int nbin = (E + CH - 1) / CH;
        k_bin<<<nbin, 256, 0, stream>>>(dst, src, t, bmeta + 16, bin1, E, partsize);
        int nb2 = (E / NXCD + CH2 - 1) / CH2 + 1;
        dim3 g2(nb2, NXCD);
        k_bin2<<<g2, 256, 0, stream>>>(bmeta, bin1, bcur2, bin2, partsize);
        k_fine2<<<NB, 256, 0, stream>>>(bstart2, bin2, payload, base, N, E);
        int gblocks = (N + 15) / 16;
        k_gather4<<<gblocks, 256, 0, stream>>>(base, (const long long*)payload,
                                               (const uint2*)y, (float*)d_out, N);
    } else if (have_y_small) {
        // R10 path: hist/scan CSR + partitioned permute; y placed right after payload
        ushort* y2p = (ushort*)((char*)d_ws + pay_off + (size_t)E * 8);
        hipMemsetAsync(cursor, 0, (size_t)N * sizeof(unsigned), stream);
        k_hist<<<1024, 256, 0, stream>>>(dst, cursor, E);
        k_scanA<<<nb, 1024, 0, stream>>>(cursor, base, bsum, N);
        k_scanB<<<1, 1024, 0, stream>>>(bsum, boff, nb);
        k_scanC<<<512, 256, 0, stream>>>(base, cursor, boff, N, E);
        int xblocks = ((M + 15) / 16 * 64 + 255) / 256;
        k_xform_mfma<<<xblocks, 256, 0, stream>>>(x_src, W, y2p, M);
        k_permute_part<<<2048, 256, 0, stream>>>(dst, src, t, cursor, payload, E, N);
        int gblocks = (N + 15) / 16;
        k_gather4<<<gblocks, 256, 0, stream>>>(base, (const long long*)payload,
                                               (const uint2*)y2p, (float*)d_out, N);
    } else {
        hipMemsetAsync(cursor, 0, (size_t)N * sizeof(unsigned), stream);
        k_hist<<<1024, 256, 0, stream>>>(dst, cursor, E);
        k_scanA<<<nb, 1024, 0, stream>>>(cursor, base, bsum, N);
        k_scanB<<<1, 1024, 0, stream>>>(bsum, boff, nb);
        k_scanC<<<512, 256, 0, stream>>>(base, cursor, boff, N, E);
        k_permute_pack<<<blocks_e, 256, 0, stream>>>(dst, src, t, cursor, payload, E);
        k_gather_fb<<<4096, 256, 0, stream>>>(base, payload, x_src, W, (float*)d_out, N);
    }
}

// Round 16
// 136.644 us; speedup vs baseline: 2.2696x; 1.0498x over previous
//
#include <hip/hip_runtime.h>
#include <math.h>

#define H 64
#define NXCD 8
#define CH 2048
#define CH2 8192
#define CAP 4096

typedef __attribute__((ext_vector_type(8))) short short8;
typedef __attribute__((ext_vector_type(4))) float f32x4;

__device__ inline ushort f2bf(float f) {
    union { float f; unsigned u; } v;
    v.f = f;
    unsigned r = v.u + 0x7FFFu + ((v.u >> 16) & 1u);
    return (ushort)(r >> 16);
}

// ================= FAST PATH =================

// ---------- Stage 0: bucket-level histogram via LDS (no random global atomics) ----------
__global__ __launch_bounds__(256) void k_count(const int* __restrict__ dst,
                                               unsigned* __restrict__ bcnt, int E, int NB) {
    __shared__ unsigned lc[1024];
    for (int j = threadIdx.x; j < NB; j += 256) lc[j] = 0;
    __syncthreads();
    int i = blockIdx.x * blockDim.x + threadIdx.x;
    int st = gridDim.x * blockDim.x;
    int E4 = E >> 2;
    const int4* d4 = (const int4*)dst;
    for (int k = i; k < E4; k += st) {
        int4 v = d4[k];
        atomicAdd(&lc[v.x >> 8], 1u);
        atomicAdd(&lc[v.y >> 8], 1u);
        atomicAdd(&lc[v.z >> 8], 1u);
        atomicAdd(&lc[v.w >> 8], 1u);
    }
    for (int k = (E4 << 2) + i; k < E; k += st) atomicAdd(&lc[dst[k] >> 8], 1u);
    __syncthreads();
    for (int j = threadIdx.x; j < NB; j += 256)
        if (lc[j]) atomicAdd(&bcnt[j], lc[j]);
}

// ---------- Stage 1: single-block scan of bucket counts -> starts, cursors, part meta ----------
__global__ __launch_bounds__(1024) void k_scan_small(const unsigned* __restrict__ bcnt,
                                                     unsigned* __restrict__ bstart2,
                                                     unsigned* __restrict__ bcur2,
                                                     unsigned* __restrict__ bmeta,
                                                     int NB, int partsize, int E) {
    __shared__ unsigned wsum[16];
    __shared__ unsigned sex[1025];
    int i = threadIdx.x;
    unsigned v = (i < NB) ? bcnt[i] : 0u;
    int lane = i & 63, w = i >> 6;
    unsigned x = v;
#pragma unroll
    for (int off = 1; off < 64; off <<= 1) {
        unsigned y = __shfl_up(x, off, 64);
        if (lane >= off) x += y;
    }
    if (lane == 63) wsum[w] = x;
    __syncthreads();
    if (i < 16) {
        unsigned s = wsum[i];
#pragma unroll
        for (int off = 1; off < 16; off <<= 1) {
            unsigned y = __shfl_up(s, off, 16);
            if ((i & 15) >= off) s += y;
        }
        wsum[i] = s;
    }
    __syncthreads();
    unsigned wbase = (w > 0) ? wsum[w - 1] : 0u;
    unsigned excl = wbase + x - v;
    sex[i] = excl;
    if (i == 0) sex[1024] = (unsigned)E;
    __syncthreads();
    if (i <= NB) bstart2[i] = sex[i];
    if (i < NB) bcur2[i] = sex[i];
    if (i <= NXCD) {
        int bidx = (i * partsize) >> 8;
        if (bidx > NB) bidx = NB;
        bmeta[i] = sex[bidx];
        if (i < NXCD) bmeta[16 + i] = sex[bidx];
    }
}

// ---------- Stage 2a: edges -> part-binned u64 (d:17|src:17|ebf16) (verified R14) ----------
__global__ __launch_bounds__(256) void k_bin(const int* __restrict__ dst,
                                             const int* __restrict__ src,
                                             const float* __restrict__ t,
                                             unsigned* __restrict__ bcur,
                                             unsigned long long* __restrict__ bin1,
                                             int E, int partsize) {
    __shared__ unsigned lcnt[NXCD];
    __shared__ unsigned lofs[NXCD];
    int e0 = blockIdx.x * CH;
    int e1 = min(e0 + CH, E);
    if (threadIdx.x < NXCD) lcnt[threadIdx.x] = 0;
    __syncthreads();
    for (int i = e0 + threadIdx.x; i < e1; i += 256) {
        int d = dst[i];
        int p = 0;
#pragma unroll
        for (int k = 1; k < NXCD; ++k) p += (d >= k * partsize);
        atomicAdd(&lcnt[p], 1u);
    }
    __syncthreads();
    if (threadIdx.x < NXCD)
        lofs[threadIdx.x] = atomicAdd(&bcur[threadIdx.x], lcnt[threadIdx.x]);
    __syncthreads();
    const float inv = 1.0f / (0.5f + 1e-8f);
    for (int i = e0 + threadIdx.x; i < e1; i += 256) {
        int d = dst[i];
        int p = 0;
#pragma unroll
        for (int k = 1; k < NXCD; ++k) p += (d >= k * partsize);
        unsigned u = atomicAdd(&lofs[p], 1u);
        unsigned eb = f2bf(__expf(t[i] * inv));
        bin1[u] = ((unsigned long long)d << 33) | ((unsigned long long)src[i] << 16)
                | (unsigned long long)eb;
    }
}

// ---------- Stage 2b: part bin -> bucket bin (verified R14) ----------
__global__ __launch_bounds__(256) void k_bin2(const unsigned* __restrict__ bmeta,
                                              const unsigned long long* __restrict__ bin1,
                                              unsigned* __restrict__ bcur2,
                                              unsigned long long* __restrict__ bin2,
                                              int partsize) {
    __shared__ unsigned lcnt[64];
    __shared__ unsigned lofs[64];
    int p = blockIdx.y;
    int b0 = (int)bmeta[p], b1 = (int)bmeta[p + 1];
    int bloc0 = (p * partsize) >> 8;
    int stridec = gridDim.x * CH2;
    for (int c0 = b0 + blockIdx.x * CH2; c0 < b1; c0 += stridec) {
        int c1 = min(c0 + CH2, b1);
        if (threadIdx.x < 64) lcnt[threadIdx.x] = 0;
        __syncthreads();
        for (int i = c0 + threadIdx.x; i < c1; i += 256) {
            int d = (int)(bin1[i] >> 33);
            atomicAdd(&lcnt[(d >> 8) - bloc0], 1u);
        }
        __syncthreads();
        if (threadIdx.x < 64) {
            unsigned cn = lcnt[threadIdx.x];
            lofs[threadIdx.x] = cn ? atomicAdd(&bcur2[bloc0 + threadIdx.x], cn) : 0u;
        }
        __syncthreads();
        for (int i = c0 + threadIdx.x; i < c1; i += 256) {
            unsigned long long u = bin1[i];
            int d = (int)(u >> 33);
            unsigned pos = atomicAdd(&lofs[(d >> 8) - bloc0], 1u);
            bin2[pos] = u;
        }
        __syncthreads();
    }
}

// ---------- Stage 2c: bucket bin -> CSR payload + base[] via LDS hist+scan+assembly ----------
__global__ __launch_bounds__(256) void k_fine2(const unsigned* __restrict__ bstart2,
                                               const unsigned long long* __restrict__ bin2,
                                               int2* __restrict__ payload,
                                               unsigned* __restrict__ base, int N, int E) {
    __shared__ int2 sPay[CAP];
    __shared__ unsigned lcnt[256];
    __shared__ unsigned lrel[256];
    __shared__ unsigned wsum[4];
    int b = blockIdx.x;
    int d0 = b << 8;
    int d1 = min(d0 + 256, N);
    int nd = d1 - d0;
    unsigned g0 = bstart2[b];
    unsigned g1 = bstart2[b + 1];
    int cnt = (int)(g1 - g0);
    int tid = threadIdx.x;
    lcnt[tid] = 0;
    __syncthreads();
    for (int i = (int)g0 + tid; i < (int)g1; i += 256)
        atomicAdd(&lcnt[(int)(bin2[i] >> 33) - d0], 1u);
    __syncthreads();
    unsigned v = lcnt[tid];
    int lane = tid & 63, w = tid >> 6;
    unsigned x = v;
#pragma unroll
    for (int off = 1; off < 64; off <<= 1) {
        unsigned y = __shfl_up(x, off, 64);
        if (lane >= off) x += y;
    }
    if (lane == 63) wsum[w] = x;
    __syncthreads();
    if (tid == 0) {
        unsigned s = 0;
#pragma unroll
        for (int k = 0; k < 4; ++k) { unsigned tq = wsum[k]; wsum[k] = s; s += tq; }
    }
    __syncthreads();
    unsigned excl = wsum[w] + x - v;
    lrel[tid] = excl;
    if (tid < nd) base[d0 + tid] = g0 + excl;
    if (b == gridDim.x - 1 && tid == 0) base[N] = (unsigned)E;
    __syncthreads();
    lcnt[tid] = excl;
    __syncthreads();
    for (int i = (int)g0 + tid; i < (int)g1; i += 256) {
        unsigned long long u = bin2[i];
        int d = (int)(u >> 33);
        int s = (int)((u >> 16) & 0x1FFFF);
        float e = __uint_as_float((unsigned)(u & 0xFFFFu) << 16);
        unsigned lpos = atomicAdd(&lcnt[d - d0], 1u);
        int2 pv = make_int2(s, __float_as_int(e));
        if (lpos < CAP) sPay[lpos] = pv;
        else payload[g0 + lpos] = pv;  // spill: correctness only
    }
    __syncthreads();
    int wn = min(cnt, CAP);
    for (int j = tid; j < wn; j += 256) payload[g0 + j] = sPay[j];
}

// ---------- Pre-transform: y(bf16) = x @ W^T via MFMA (verified R8) ----------
// Block 0 additionally zeroes bcnt (replaces a pathological 40us fillBuffer dispatch;
// same-stream ordering guarantees bcnt is zero before k_count runs).
__global__ __launch_bounds__(256) void k_xform_mfma(const float* __restrict__ x,
                                                    const float* __restrict__ W,
                                                    ushort* __restrict__ y, int M,
                                                    unsigned* __restrict__ bcnt, int NB) {
    if (bcnt != nullptr && blockIdx.x == 0) {
        for (int j = threadIdx.x; j < NB; j += 256) bcnt[j] = 0u;
    }
    int wid = (blockIdx.x * blockDim.x + threadIdx.x) >> 6;
    int lane = threadIdx.x & 63;
    int n0 = wid * 16;
    if (n0 >= M) return;
    int r = lane & 15, g = lane >> 4;

    short8 bfrag[4][2];
#pragma unroll
    for (int ct = 0; ct < 4; ++ct) {
#pragma unroll
        for (int kh = 0; kh < 2; ++kh) {
            const float* wp = &W[(size_t)(ct * 16 + r) * 64 + kh * 32 + g * 8];
            float4 w0 = *(const float4*)wp;
            float4 w1 = *(const float4*)(wp + 4);
            short8 bf;
            bf[0] = (short)f2bf(w0.x); bf[1] = (short)f2bf(w0.y);
            bf[2] = (short)f2bf(w0.z); bf[3] = (short)f2bf(w0.w);
            bf[4] = (short)f2bf(w1.x); bf[5] = (short)f2bf(w1.y);
            bf[6] = (short)f2bf(w1.z); bf[7] = (short)f2bf(w1.w);
            bfrag[ct][kh] = bf;
        }
    }
    int xr = n0 + r;
    if (xr >= M) xr = M - 1;
    const float* xp = &x[(size_t)xr * 64 + g * 8];
    short8 afrag[2];
#pragma unroll
    for (int kh = 0; kh < 2; ++kh) {
        float4 a0 = *(const float4*)(xp + kh * 32);
        float4 a1 = *(const float4*)(xp + kh * 32 + 4);
        short8 af;
        af[0] = (short)f2bf(a0.x); af[1] = (short)f2bf(a0.y);
        af[2] = (short)f2bf(a0.z); af[3] = (short)f2bf(a0.w);
        af[4] = (short)f2bf(a1.x); af[5] = (short)f2bf(a1.y);
        af[6] = (short)f2bf(a1.z); af[7] = (short)f2bf(a1.w);
        afrag[kh] = af;
    }
#pragma unroll
    for (int ct = 0; ct < 4; ++ct) {
        f32x4 acc = {0.f, 0.f, 0.f, 0.f};
        acc = __builtin_amdgcn_mfma_f32_16x16x32_bf16(afrag[0], bfrag[ct][0], acc, 0, 0, 0);
        acc = __builtin_amdgcn_mfma_f32_16x16x32_bf16(afrag[1], bfrag[ct][1], acc, 0, 0, 0);
#pragma unroll
        for (int q = 0; q < 4; ++q) {
            int row = n0 + g * 4 + q;
            if (row < M) y[(size_t)row * 64 + ct * 16 + r] = f2bf(acc[q]);
        }
    }
}

// ---------- Pass 3: weighted gather, 4 dests/wave, 16 lanes/dest (verified R10) ----------
__global__ __launch_bounds__(256) void k_gather4(const unsigned* __restrict__ base,
                                                 const long long* __restrict__ payload,
                                                 const uint2* __restrict__ y2,
                                                 float* __restrict__ out, int N) {
    int tid = blockIdx.x * blockDim.x + threadIdx.x;
    int lane = threadIdx.x & 63;
    int g = lane >> 4, f = lane & 15;
    int d = (tid >> 6) * 4 + g;
    if (d >= N) return;
    unsigned r0 = base[d], r1 = base[d + 1];
    int deg = (int)(r1 - r0);
    float acc0 = 0.f, acc1 = 0.f, acc2 = 0.f, acc3 = 0.f, ssum = 0.f;
    for (int it = 0; it < deg; it += 4) {
        float e[4];
        int s[4];
#pragma unroll
        for (int k2 = 0; k2 < 4; ++k2) {
            long long pl = __builtin_nontemporal_load(&payload[r0 + it + k2]);
            bool ok = (it + k2) < deg;
            e[k2] = ok ? __int_as_float((int)(pl >> 32)) : 0.f;
            s[k2] = ok ? (int)(pl & 0xFFFFFFFFll) : 0;
            ssum += e[k2];
        }
        uint2 v[4];
#pragma unroll
        for (int k2 = 0; k2 < 4; ++k2) v[k2] = y2[(size_t)s[k2] * 16 + f];
#pragma unroll
        for (int k2 = 0; k2 < 4; ++k2) {
            float x0 = __uint_as_float(v[k2].x << 16);
            float x1 = __uint_as_float(v[k2].x & 0xFFFF0000u);
            float x2 = __uint_as_float(v[k2].y << 16);
            float x3 = __uint_as_float(v[k2].y & 0xFFFF0000u);
            acc0 = fmaf(e[k2], x0, acc0);
            acc1 = fmaf(e[k2], x1, acc1);
            acc2 = fmaf(e[k2], x2, acc2);
            acc3 = fmaf(e[k2], x3, acc3);
        }
    }
    float rs = 1.0f / (ssum + 1e-16f);
    f32x4 o = {acc0 * rs, acc1 * rs, acc2 * rs, acc3 * rs};
    __builtin_nontemporal_store(o, (f32x4*)&out[(size_t)d * H + f * 4]);
}

// ================= FALLBACK PATH (R10-proven) =================

__global__ void k_hist(const int* __restrict__ dst, unsigned* __restrict__ cnt, int E) {
    int i = blockIdx.x * blockDim.x + threadIdx.x;
    int st = gridDim.x * blockDim.x;
    int E4 = E >> 2;
    const int4* d4 = (const int4*)dst;
    for (int k = i; k < E4; k += st) {
        int4 v = d4[k];
        atomicAdd(&cnt[v.x], 1u);
        atomicAdd(&cnt[v.y], 1u);
        atomicAdd(&cnt[v.z], 1u);
        atomicAdd(&cnt[v.w], 1u);
    }
    for (int k = (E4 << 2) + i; k < E; k += st) atomicAdd(&cnt[dst[k]], 1u);
}

__global__ __launch_bounds__(1024) void k_scanA(const unsigned* __restrict__ cnt,
                                                unsigned* __restrict__ base,
                                                unsigned* __restrict__ bsum, int N) {
    __shared__ unsigned wsum[16];
    int i = blockIdx.x * 1024 + threadIdx.x;
    unsigned v = (i < N) ? cnt[i] : 0u;
    int lane = threadIdx.x & 63, w = threadIdx.x >> 6;
    unsigned x = v;
#pragma unroll
    for (int off = 1; off < 64; off <<= 1) {
        unsigned y = __shfl_up(x, off, 64);
        if (lane >= off) x += y;
    }
    if (lane == 63) wsum[w] = x;
    __syncthreads();
    if (threadIdx.x < 16) {
        unsigned s = wsum[threadIdx.x];
#pragma unroll
        for (int off = 1; off < 16; off <<= 1) {
            unsigned y = __shfl_up(s, off, 16);
            if ((threadIdx.x & 15) >= off) s += y;
        }
        wsum[threadIdx.x] = s;
    }
    __syncthreads();
    unsigned wbase = (w > 0) ? wsum[w - 1] : 0u;
    if (i < N) base[i] = wbase + x - v;
    if (threadIdx.x == 1023) bsum[blockIdx.x] = wsum[15];
}

__global__ __launch_bounds__(1024) void k_scanB(const unsigned* __restrict__ bsum,
                                                unsigned* __restrict__ boff, int nb) {
    __shared__ unsigned wsum[16];
    int i = threadIdx.x;
    unsigned v = (i < nb) ? bsum[i] : 0u;
    int lane = i & 63, w = i >> 6;
    unsigned x = v;
#pragma unroll
    for (int off = 1; off < 64; off <<= 1) {
        unsigned y = __shfl_up(x, off, 64);
        if (lane >= off) x += y;
    }
    if (lane == 63) wsum[w] = x;
    __syncthreads();
    if (i < 16) {
        unsigned s = wsum[i];
#pragma unroll
        for (int off = 1; off < 16; off <<= 1) {
            unsigned y = __shfl_up(s, off, 16);
            if ((i & 15) >= off) s += y;
        }
        wsum[i] = s;
    }
    __syncthreads();
    unsigned wbase = (w > 0) ? wsum[w - 1] : 0u;
    if (i < nb) boff[i] = wbase + x - v;
}

__global__ void k_scanC(unsigned* __restrict__ base, unsigned* __restrict__ cursor,
                        const unsigned* __restrict__ boff, int N, int E) {
    int i = blockIdx.x * blockDim.x + threadIdx.x;
    int st = gridDim.x * blockDim.x;
    for (; i < N; i += st) {
        unsigned b = base[i] + boff[i >> 10];
        base[i] = b;
        cursor[i] = b;
    }
    if (blockIdx.x == 0 && threadIdx.x == 0) base[N] = (unsigned)E;
}

__global__ void k_permute_part(const int* __restrict__ dst, const int* __restrict__ src,
                               const float* __restrict__ t, unsigned* __restrict__ cursor,
                               int2* __restrict__ payload, int E, int N) {
    const float inv = 1.0f / (0.5f + 1e-8f);
    int part = blockIdx.x & (NXCD - 1);
    int nslice = gridDim.x >> 3;
    int sblk = blockIdx.x >> 3;
    int lo = (int)((long long)part * N / NXCD);
    int hi = (int)((long long)(part + 1) * N / NXCD);
    int e0 = (int)((long long)sblk * E / nslice);
    int e1 = (int)((long long)(sblk + 1) * E / nslice);
    for (int i = e0 + threadIdx.x; i < e1; i += blockDim.x) {
        int d = dst[i];
        if (d >= lo && d < hi) {
            unsigned pos = atomicAdd(&cursor[d], 1u);
            float e = __expf(t[i] * inv);
            payload[pos] = make_int2(src[i], __float_as_int(e));
        }
    }
}

__global__ void k_permute_pack(const int* __restrict__ dst, const int* __restrict__ src,
                               const float* __restrict__ t, unsigned* __restrict__ cursor,
                               int2* __restrict__ payload, int E) {
    const float inv = 1.0f / (0.5f + 1e-8f);
    int i = blockIdx.x * blockDim.x + threadIdx.x;
    int st = gridDim.x * blockDim.x;
    for (; i < E; i += st) {
        unsigned pos = atomicAdd(&cursor[dst[i]], 1u);
        float e = __expf(t[i] * inv);
        payload[pos] = make_int2(src[i], __float_as_int(e));
    }
}

__global__ __launch_bounds__(256) void k_gather_fb(const unsigned* __restrict__ base,
                                                   const int2* __restrict__ payload,
                                                   const float* __restrict__ x_src,
                                                   const float* __restrict__ W,
                                                   float* __restrict__ out, int N) {
    __shared__ float wt[H * H];
    for (int idx = threadIdx.x; idx < H * H; idx += blockDim.x) {
        int j = idx >> 6, k = idx & 63;
        wt[k * H + j] = W[idx];
    }
    __syncthreads();
    int lane = threadIdx.x & 63;
    int wid = (blockIdx.x * blockDim.x + threadIdx.x) >> 6;
    int nw = (gridDim.x * blockDim.x) >> 6;
    for (int d = wid; d < N; d += nw) {
        unsigned r0 = base[d], r1 = base[d + 1];
        int deg = (int)(r1 - r0);
        float acc = 0.0f, ssum = 0.0f;
        for (int c = 0; c < deg; c += 64) {
            int j = c + lane;
            int cd = min(64, deg - c);
            float e = 0.0f;
            int sidx = 0;
            if (j < deg) {
                int2 p = payload[r0 + j];
                sidx = p.x;
                e = __int_as_float(p.y);
            }
            float cs = e;
#pragma unroll
            for (int off = 32; off >= 1; off >>= 1) cs += __shfl_xor(cs, off, 64);
            ssum += cs;
            for (int q = 0; q < cd; q += 8) {
                float a[8];
                int sv[8];
                float v[8];
#pragma unroll
                for (int u = 0; u < 8; ++u) {
                    a[u] = __shfl(e, q + u, 64);
                    sv[u] = __shfl(sidx, q + u, 64);
                }
#pragma unroll
                for (int u = 0; u < 8; ++u) v[u] = x_src[(size_t)sv[u] * H + lane];
#pragma unroll
                for (int u = 0; u < 8; ++u) acc = fmaf(a[u], v[u], acc);
            }
        }
        acc *= 1.0f / (ssum + 1e-16f);
        float o = 0.0f;
#pragma unroll
        for (int k = 0; k < H; ++k) o = fmaf(__shfl(acc, k, 64), wt[k * H + lane], o);
        out[(size_t)d * H + lane] = o;
    }
}

extern "C" void kernel_launch(void* const* d_in, const int* in_sizes, int n_in,
                              void* d_out, int out_size, void* d_ws, size_t ws_size,
                              hipStream_t stream) {
    const float* x_src = (const float*)d_in[0];
    const float* W = (const float*)d_in[2];
    const int* edge_index = (const int*)d_in[3];
    const float* t = (const float*)d_in[4];

    int E = in_sizes[4];
    int N = in_sizes[1] / H;  // N_DST
    int M = in_sizes[0] / H;  // N_SRC
    const int* src = edge_index;
    const int* dst = edge_index + E;

    // ws layout (u32): base[N+1] | cursor[N] | bsum[1024] | boff[1024] | bmeta[32]
    //                 | bcnt[1024] | bstart2[1056] | bcur2[1056]
    //                 | payload int2[E] (alias bin1 u64[E]) | bin2 u64[E] | y bf16[M*H]
    unsigned* base = (unsigned*)d_ws;
    unsigned* cursor = base + (size_t)N + 1;
    unsigned* bsum = cursor + N;
    unsigned* boff = bsum + 1024;
    unsigned* bmeta = boff + 1024;
    unsigned* bcnt = bmeta + 32;
    unsigned* bstart2 = bcnt + 1024;
    unsigned* bcur2 = bstart2 + 1056;
    size_t head_u32 = (size_t)(2 * N + 1) + 1024 + 1024 + 32 + 1024 + 1056 + 1056;
    size_t pay_off = (head_u32 * 4 + 15) & ~(size_t)15;
    int2* payload = (int2*)((char*)d_ws + pay_off);
    unsigned long long* bin1 = (unsigned long long*)payload;  // alias (dead before k_fine2 writes)
    size_t b2_off = (pay_off + (size_t)E * 8 + 15) & ~(size_t)15;
    unsigned long long* bin2 = (unsigned long long*)((char*)d_ws + b2_off);
    size_t y_off = b2_off + (size_t)E * 8;
    ushort* y = (ushort*)((char*)d_ws + y_off);

    bool have_payload = (ws_size >= pay_off + (size_t)E * 8 + 32);
    bool have_y_small = (ws_size >= pay_off + (size_t)E * 8 + (size_t)M * H * 2 + 32);
    bool have_full = (ws_size >= y_off + (size_t)M * H * 2);
    bool packable = (M < (1 << 17)) && (N < (1 << 17));

    int nb = (N + 1023) / 1024;
    int ps0 = (N + NXCD - 1) / NXCD;
    int partsize = (ps0 + 255) & ~255;  // 256-aligned so buckets nest in parts
    int NB = (N + 255) >> 8;

    int blocks_e = (E + 255) / 256;
    if (blocks_e > 2048) blocks_e = 2048;

    if (have_full && packable && NB <= 1024) {
        int xblocks = ((M + 15) / 16 * 64 + 255) / 256;
        k_xform_mfma<<<xblocks, 256, 0, stream>>>(x_src, W, y, M, bcnt, NB);
        k_count<<<1024, 256, 0, stream>>>(dst, bcnt, E, NB);
        k_scan_small<<<1, 1024, 0, stream>>>(bcnt, bstart2, bcur2, bmeta, NB, partsize, E);
        int nbin = (E + CH - 1) / CH;
        k_bin<<<nbin, 256, 0, stream>>>(dst, src, t, bmeta + 16, bin1, E, partsize);
        int nb2 = (E / NXCD + CH2 - 1) / CH2 + 1;
        dim3 g2(nb2, NXCD);
        k_bin2<<<g2, 256, 0, stream>>>(bmeta, bin1, bcur2, bin2, partsize);
        k_fine2<<<NB, 256, 0, stream>>>(bstart2, bin2, payload, base, N, E);
        int gblocks = (N + 15) / 16;
        k_gather4<<<gblocks, 256, 0, stream>>>(base, (const long long*)payload,
                                               (const uint2*)y, (float*)d_out, N);
    } else if (have_y_small) {
        // R10 path: hist/scan CSR + partitioned permute; y placed right after payload
        ushort* y2p = (ushort*)((char*)d_ws + pay_off + (size_t)E * 8);
        hipMemsetAsync(cursor, 0, (size_t)N * sizeof(unsigned), stream);
        k_hist<<<1024, 256, 0, stream>>>(dst, cursor, E);
        k_scanA<<<nb, 1024, 0, stream>>>(cursor, base, bsum, N);
        k_scanB<<<1, 1024, 0, stream>>>(bsum, boff, nb);
        k_scanC<<<512, 256, 0, stream>>>(base, cursor, boff, N, E);
        int xblocks = ((M + 15) / 16 * 64 + 255) / 256;
        k_xform_mfma<<<xblocks, 256, 0, stream>>>(x_src, W, y2p, M, nullptr, 0);
        k_permute_part<<<2048, 256, 0, stream>>>(dst, src, t, cursor, payload, E, N);
        int gblocks = (N + 15) / 16;
        k_gather4<<<gblocks, 256, 0, stream>>>(base, (const long long*)payload,
                                               (const uint2*)y2p, (float*)d_out, N);
    } else {
        hipMemsetAsync(cursor, 0, (size_t)N * sizeof(unsigned), stream);
        k_hist<<<1024, 256, 0, stream>>>(dst, cursor, E);
        k_scanA<<<nb, 1024, 0, stream>>>(cursor, base, bsum, N);
        k_scanB<<<1, 1024, 0, stream>>>(bsum, boff, nb);
        k_scanC<<<512, 256, 0, stream>>>(base, cursor, boff, N, E);
        k_permute_pack<<<blocks_e, 256, 0, stream>>>(dst, src, t, cursor, payload, E);
        k_gather_fb<<<4096, 256, 0, stream>>>(base, payload, x_src, W, (float*)d_out, N);
    }
}